// Round 8
// baseline (633.374 us; speedup 1.0000x reference)
//
#include <hip/hip_runtime.h>
#include <stdint.h>

// LinearSelfAttention: out = ((phi(xWq) @ (phi(xWk)^T V)) / Z) @ Wo
// B=4 S=8192 H=16 Dh=64 F=128 Dm=1024. All GEMMs bf16-MFMA/fp32-acc.
// R8: QKV GEMM -> 256^2 tile, 4-phase/K-tile counted-vmcnt pipeline (T3+T4),
//     2dbuf x 2 K-halves, rotation-swizzled LDS, setprio (T5).
//     Epilogue = R5's validated per-wave phi patches. gemm_out stays 128^2.

#define DEVINL __device__ __forceinline__

typedef float f32x4 __attribute__((ext_vector_type(4)));
typedef __bf16 bf16x8 __attribute__((ext_vector_type(8)));
typedef unsigned short u16;

DEVINL u16 f2bf(float f) {
  union { float f; uint32_t u; } v; v.f = f;
  uint32_t u = v.u;
  u += 0x7fffu + ((u >> 16) & 1u);   // round-to-nearest-even
  return (u16)(u >> 16);
}
DEVINL float bf2f(u16 h) {
  union { uint32_t u; float f; } v; v.u = ((uint32_t)h) << 16;
  return v.f;
}

#define GLOAD16(gp, lp) __builtin_amdgcn_global_load_lds( \
    (const __attribute__((address_space(1))) unsigned int*)(gp), \
    (__attribute__((address_space(3))) unsigned int*)(lp), 16, 0, 0)

// ---- linear staging (kv_partial / qkv_div) ----
template <int ROWS>
DEVINL void stage_r128(const uint8_t* g, size_t stride, u16* lds, int wave, int lane) {
#pragma unroll
  for (int j = 0; j < ROWS / 32; ++j) {
    int row = wave * (ROWS / 4) + j * 8 + (lane >> 3);
    GLOAD16(g + (size_t)row * stride + (size_t)(lane & 7) * 16,
            (uint8_t*)lds + (size_t)(wave * (ROWS / 4) + j * 8) * 128);
  }
}
template <int ROWS>
DEVINL void stage_r256(const uint8_t* g, size_t stride, u16* lds, int wave, int lane) {
#pragma unroll
  for (int j = 0; j < ROWS / 16; ++j) {
    int row = wave * (ROWS / 4) + j * 4 + (lane >> 4);
    GLOAD16(g + (size_t)row * stride + (size_t)(lane & 15) * 16,
            (uint8_t*)lds + (size_t)(wave * (ROWS / 4) + j * 4) * 256);
  }
}

// ---- 128^2 swizzled machinery (gemm_out) ----
DEVINL void stage128_sw(const uint8_t* g, size_t stride, u16* lds, int wave, int lane) {
  const int c = (lane & 7) ^ (lane >> 3);
#pragma unroll
  for (int j = 0; j < 4; ++j) {
    int row = wave * 32 + j * 8 + (lane >> 3);
    GLOAD16(g + (size_t)row * stride + (size_t)c * 16,
            (uint8_t*)lds + (size_t)(wave * 32 + j * 8) * 128);
  }
}
DEVINL void mma128_sw(const u16* As, const u16* Bs, f32x4 acc[4][4],
                      int wr, int wc, int lane) {
#pragma unroll
  for (int kk = 0; kk < 2; ++kk) {
    const int cw = kk * 4 + (lane >> 4);
    const int sw = (cw ^ (lane & 7)) * 8;
    bf16x8 a[4], b[4];
#pragma unroll
    for (int m = 0; m < 4; ++m)
      a[m] = *(const bf16x8*)&As[(size_t)(wr * 64 + m * 16 + (lane & 15)) * 64 + sw];
#pragma unroll
    for (int n = 0; n < 4; ++n)
      b[n] = *(const bf16x8*)&Bs[(size_t)(wc * 64 + n * 16 + (lane & 15)) * 64 + sw];
#pragma unroll
    for (int m = 0; m < 4; ++m)
#pragma unroll
      for (int n = 0; n < 4; ++n)
        acc[m][n] = __builtin_amdgcn_mfma_f32_16x16x32_bf16(a[m], b[n], acc[m][n], 0, 0, 0);
  }
}

// ---- 256^2 pipeline: stage one K-half (256 rows x 32 k) with rotation swizzle.
// LDS slot sl of row r holds global chunk (sl - r - (r>>2)) & 3. 2 loads/thread.
DEVINL void stage_half(const u16* g, int koffB, u16* hb, int tid) {
#pragma unroll
  for (int l = 0; l < 2; ++l) {
    int idx = l * 512 + tid;
    int row = idx >> 2, sl = idx & 3;
    int c = (sl - row - (row >> 2)) & 3;
    GLOAD16((const uint8_t*)g + (size_t)row * 2048 + koffB + c * 16,
            (uint8_t*)hb + (size_t)(idx & ~63) * 16);
  }
}

// ---------------- prep kernels ----------------

__global__ __launch_bounds__(256) void cast_x_kernel(
    const float* __restrict__ src, u16* __restrict__ dst, long n4) {
  long i = (long)blockIdx.x * 256 + threadIdx.x;
  const long stride = (long)gridDim.x * 256;
  const float4* s4 = (const float4*)src;
  uint2* d4 = (uint2*)dst;
  for (; i < n4; i += stride) {
    float4 v = s4[i];
    uint2 o;
    o.x = (uint32_t)f2bf(v.x) | ((uint32_t)f2bf(v.y) << 16);
    o.y = (uint32_t)f2bf(v.z) | ((uint32_t)f2bf(v.w) << 16);
    d4[i] = o;
  }
}

__global__ __launch_bounds__(256) void transpose_cast_kernel(
    const float* __restrict__ src, u16* __restrict__ dst, int R, int C) {
  __shared__ float tile[32 * 33];
  const int ntr = R >> 5;
  const int tr = blockIdx.x % ntr, tc = blockIdx.x / ntr;
  const int tid = threadIdx.x;
  {
    int r = tid >> 3, c4 = (tid & 7) * 4;
    float4 v = *(const float4*)&src[(size_t)(tr * 32 + r) * C + tc * 32 + c4];
    tile[r * 33 + c4 + 0] = v.x;
    tile[r * 33 + c4 + 1] = v.y;
    tile[r * 33 + c4 + 2] = v.z;
    tile[r * 33 + c4 + 3] = v.w;
  }
  __syncthreads();
  {
    int c = tid >> 3, r4 = (tid & 7) * 4;
    uint2 o;
    o.x = (uint32_t)f2bf(tile[(r4 + 0) * 33 + c]) |
          ((uint32_t)f2bf(tile[(r4 + 1) * 33 + c]) << 16);
    o.y = (uint32_t)f2bf(tile[(r4 + 2) * 33 + c]) |
          ((uint32_t)f2bf(tile[(r4 + 3) * 33 + c]) << 16);
    *(uint2*)&dst[(size_t)(tc * 32 + c) * R + tr * 32 + r4] = o;
  }
}

// ---------------- QKV GEMM (256^2, 4-phase counted-vmcnt) + fused phi ----------------
// N = 3072: tn 0..3 Q, 4..7 K, 8..11 V. Wave (wr 0..1, wc 0..3): C rows
// wr*128+[0,128), cols wc*64+[0,64) -> wave owns head (tn&3)*4+wc entirely.
__global__ __launch_bounds__(512, 2) void gemm_qkv_phi_kernel(
    const u16* __restrict__ xb, const u16* __restrict__ wT,
    const u16* __restrict__ rfT,
    u16* __restrict__ Qp, u16* __restrict__ KpT, u16* __restrict__ VhT) {
  __shared__ u16 smem[65536];   // 128 KiB: A dbuf 0..32767, B dbuf 32768..65535
  const int tid = threadIdx.x, lane = tid & 63, wave = tid >> 6;
  const int wr = wave >> 2, wc = wave & 3;
  const int xcd = blockIdx.x & 7, ii = blockIdx.x >> 3;   // 1536 = 8*192
  const int tn = ii % 12, tm = xcd * 16 + ii / 12;
  const int tensor = tn >> 2;
  const u16* gA = xb + (size_t)tm * 256 * 1024;
  const u16* gB = wT + (size_t)tn * 256 * 1024;
  // lane-uniform rotated slot for frag reads (chunk cw = lane>>4)
  const int slot4 = ((lane >> 4) + (lane & 3) + ((lane >> 2) & 3)) & 3;

  f32x4 acc[8][4];
#pragma unroll
  for (int m = 0; m < 8; ++m)
#pragma unroll
    for (int n = 0; n < 4; ++n) acc[m][n] = (f32x4){0.f, 0.f, 0.f, 0.f};

  // prologue: tile 0 all 4 halves; retire k0 halves; barrier
  stage_half(gA, 0, smem, tid);                 // A k0 -> buf0 half0
  stage_half(gB, 0, smem + 32768, tid);         // B k0
  stage_half(gA, 64, smem + 8192, tid);         // A k1 -> buf0 half1
  stage_half(gB, 64, smem + 40960, tid);        // B k1
  asm volatile("s_waitcnt vmcnt(4)" ::: "memory");
  __builtin_amdgcn_s_barrier();
  asm volatile("" ::: "memory");

  for (int t = 0; t < 16; ++t) {
    const int buf = t & 1;
    u16* Ab = smem + buf * 16384;               // halves at +0 / +8192
    u16* Bb = smem + 32768 + buf * 16384;
    u16* AbN = smem + (buf ^ 1) * 16384;
    u16* BbN = smem + 32768 + (buf ^ 1) * 16384;
    const int koffN = (t + 1) * 128;            // bytes into K dim for tile t+1
#pragma unroll
    for (int p = 0; p < 4; ++p) {
      const int ks = p >> 1, mh = p & 1;
      const u16* Ah = Ab + ks * 8192;
      const u16* Bh = Bb + ks * 8192;
      bf16x8 bfr[4], afr[4];
#pragma unroll
      for (int n = 0; n < 4; ++n)
        bfr[n] = *(const bf16x8*)&Bh[(size_t)(wc * 64 + n * 16 + (lane & 15)) * 32 + slot4 * 8];
#pragma unroll
      for (int m4 = 0; m4 < 4; ++m4)
        afr[m4] = *(const bf16x8*)&Ah[(size_t)(wr * 128 + (mh * 4 + m4) * 16 + (lane & 15)) * 32 + slot4 * 8];
      if (t < 15) {
        if (p == 0) stage_half(gA, koffN,      AbN,        tid);
        if (p == 1) stage_half(gB, koffN,      BbN,        tid);
        if (p == 2) stage_half(gA, koffN + 64, AbN + 8192, tid);
        if (p == 3) stage_half(gB, koffN + 64, BbN + 8192, tid);
      }
      if (p == 1) {
        if (t == 15) asm volatile("s_waitcnt vmcnt(0)" ::: "memory");
        else         asm volatile("s_waitcnt vmcnt(4)" ::: "memory");
      } else if (p == 3) {
        asm volatile("s_waitcnt vmcnt(4)" ::: "memory");
      }
      __builtin_amdgcn_s_barrier();
      asm volatile("" ::: "memory");
      __builtin_amdgcn_s_setprio(1);
#pragma unroll
      for (int m4 = 0; m4 < 4; ++m4)
#pragma unroll
        for (int n = 0; n < 4; ++n)
          acc[mh * 4 + m4][n] =
              __builtin_amdgcn_mfma_f32_16x16x32_bf16(afr[m4], bfr[n], acc[mh * 4 + m4][n], 0, 0, 0);
      __builtin_amdgcn_s_setprio(0);
      __builtin_amdgcn_s_barrier();
      asm volatile("" ::: "memory");
    }
  }

  // ---- epilogue (R5-validated): per-wave private patch [*][72] (4608 u16) ----
  u16* patch = smem + (size_t)wave * 4608;
  const int b = tm >> 5;
  const int h = (tn & 3) * 4 + wc;
  const size_t bh = (size_t)b * 16 + h;
  const int sb = (tm & 31) * 256 + wr * 128;
  const float SC = 0.088388347648318447f;  // 128^-0.5

  if (tensor == 2) {
    // V -> VhT[b,h,d,s]; per s-half: patch [64 d][72] cols s_l
#pragma unroll
    for (int sh = 0; sh < 2; ++sh) {
#pragma unroll
      for (int q = 0; q < 4; ++q)
#pragma unroll
        for (int n = 0; n < 4; ++n) {
          int d = n * 16 + (lane & 15);
          int s_l = q * 16 + (lane >> 4) * 4;
#pragma unroll
          for (int r = 0; r < 4; ++r)
            patch[d * 72 + s_l + r] = f2bf(acc[sh * 4 + q][n][r]);
        }
#pragma unroll
      for (int it = 0; it < 8; ++it) {
        int d = it * 8 + (lane >> 3);
        *(uint4*)&VhT[(bh * 64 + d) * 8192 + sb + sh * 64 + (lane & 7) * 8] =
            *(const uint4*)&patch[d * 72 + (lane & 7) * 8];
      }
    }
    return;
  }

  // Q/K: phi per 64-row chunk
#pragma unroll
  for (int ch = 0; ch < 2; ++ch) {
#pragma unroll
    for (int q = 0; q < 4; ++q)
#pragma unroll
      for (int n = 0; n < 4; ++n) {
        int d = n * 16 + (lane & 15);
        int s_l = q * 16 + (lane >> 4) * 4;
#pragma unroll
        for (int r = 0; r < 4; ++r)
          patch[(s_l + r) * 72 + d] = f2bf(acc[ch * 4 + q][n][r]);
      }
    bf16x8 af[4][2];
#pragma unroll
    for (int fm = 0; fm < 4; ++fm)
#pragma unroll
      for (int kk = 0; kk < 2; ++kk)
        af[fm][kk] = *(const bf16x8*)&patch[(size_t)(fm * 16 + (lane & 15)) * 72 +
                                            kk * 32 + (lane >> 4) * 8];
#pragma unroll
    for (int fh = 0; fh < 2; ++fh) {
      f32x4 pacc[4][4];
#pragma unroll
      for (int fm = 0; fm < 4; ++fm)
#pragma unroll
        for (int nn = 0; nn < 4; ++nn) pacc[fm][nn] = (f32x4){0.f, 0.f, 0.f, 0.f};
#pragma unroll
      for (int kk = 0; kk < 2; ++kk)
#pragma unroll
        for (int nn = 0; nn < 4; ++nn) {
          int f = (fh * 4 + nn) * 16 + (lane & 15);
          bf16x8 bb = *(const bf16x8*)&rfT[(size_t)f * 64 + kk * 32 + (lane >> 4) * 8];
#pragma unroll
          for (int fm = 0; fm < 4; ++fm)
            pacc[fm][nn] = __builtin_amdgcn_mfma_f32_16x16x32_bf16(af[fm][kk], bb, pacc[fm][nn], 0, 0, 0);
        }
#pragma unroll
      for (int fm = 0; fm < 4; ++fm)
#pragma unroll
        for (int nn = 0; nn < 4; ++nn) {
          int f_l = nn * 16 + (lane & 15);
          int s_l = fm * 16 + (lane >> 4) * 4;
#pragma unroll
          for (int r = 0; r < 4; ++r) {
            float pv = pacc[fm][nn][r];
            float v = (fh == 0 ? __cosf(pv) : __sinf(pv)) * SC;
            if (tensor == 0) patch[(s_l + r) * 72 + f_l] = f2bf(v);
            else             patch[f_l * 72 + s_l + r]   = f2bf(v);
          }
        }
      if (tensor == 0) {
#pragma unroll
        for (int it = 0; it < 8; ++it) {
          int s_l = it * 8 + (lane >> 3);
          *(uint4*)&Qp[(bh * 8192 + sb + ch * 64 + s_l) * 128 + fh * 64 + (lane & 7) * 8] =
              *(const uint4*)&patch[s_l * 72 + (lane & 7) * 8];
        }
      } else {
#pragma unroll
        for (int it = 0; it < 8; ++it) {
          int f_l = it * 8 + (lane >> 3);
          *(uint4*)&KpT[(bh * 128 + fh * 64 + f_l) * 8192 + sb + ch * 64 + (lane & 7) * 8] =
              *(const uint4*)&patch[f_l * 72 + (lane & 7) * 8];
        }
      }
    }
  }
}

// ---------------- KV = Kp^T V + Ksum, 16 s-chunks ----------------
__global__ __launch_bounds__(256) void kv_partial_kernel(
    const u16* __restrict__ KpT, const u16* __restrict__ VhT,
    float* __restrict__ partial) {
  __shared__ u16 smem2[12288];
  __shared__ float ksmem[256];
  u16* As = smem2;        // [128 f][64 s]
  u16* Bs = smem2 + 8192; // [64 d][64 s]
  const int tid = threadIdx.x, lane = tid & 63, wave = tid >> 6;
  const int bh = blockIdx.x >> 4, ch = blockIdx.x & 15;
  const uint8_t* aB = (const uint8_t*)(KpT + (size_t)bh * 128 * 8192 + ch * 512);
  const uint8_t* bB = (const uint8_t*)(VhT + (size_t)bh * 64 * 8192 + ch * 512);

  f32x4 acc[2][4];
#pragma unroll
  for (int m = 0; m < 2; ++m)
#pragma unroll
    for (int n = 0; n < 4; ++n) acc[m][n] = (f32x4){0.f, 0.f, 0.f, 0.f};
  float ks = 0.f;
  const int fK = tid >> 1, sO = (tid & 1) * 32;

  for (int t = 0; t < 8; ++t) {
    stage_r128<128>(aB + t * 128, 16384, As, wave, lane);
    stage_r128<64>(bB + t * 128, 16384, Bs, wave, lane);
    __syncthreads();
#pragma unroll
    for (int i = 0; i < 4; ++i) {
      uint4 v = *(const uint4*)&As[fK * 64 + sO + i * 8];
      ks += bf2f((u16)(v.x & 0xffff)) + bf2f((u16)(v.x >> 16));
      ks += bf2f((u16)(v.y & 0xffff)) + bf2f((u16)(v.y >> 16));
      ks += bf2f((u16)(v.z & 0xffff)) + bf2f((u16)(v.z >> 16));
      ks += bf2f((u16)(v.w & 0xffff)) + bf2f((u16)(v.w >> 16));
    }
#pragma unroll
    for (int kk = 0; kk < 2; ++kk) {
      const int ko = kk * 32 + (lane >> 4) * 8;
      bf16x8 a[2], bb[4];
#pragma unroll
      for (int m = 0; m < 2; ++m)
        a[m] = *(const bf16x8*)&As[(size_t)(wave * 32 + m * 16 + (lane & 15)) * 64 + ko];
#pragma unroll
      for (int n = 0; n < 4; ++n)
        bb[n] = *(const bf16x8*)&Bs[(size_t)(n * 16 + (lane & 15)) * 64 + ko];
#pragma unroll
      for (int m = 0; m < 2; ++m)
#pragma unroll
        for (int n = 0; n < 4; ++n)
          acc[m][n] = __builtin_amdgcn_mfma_f32_16x16x32_bf16(a[m], bb[n], acc[m][n], 0, 0, 0);
    }
    __syncthreads();
  }

  float* pb = partial + (size_t)blockIdx.x * (128 * 65);
#pragma unroll
  for (int m = 0; m < 2; ++m)
#pragma unroll
    for (int n = 0; n < 4; ++n) {
      int d = n * 16 + (lane & 15);
#pragma unroll
      for (int r = 0; r < 4; ++r) {
        int f = wave * 32 + m * 16 + (lane >> 4) * 4 + r;
        pb[f * 65 + d] = acc[m][n][r];
      }
    }
  ksmem[tid] = ks;
  __syncthreads();
  if (tid < 128) pb[tid * 65 + 64] = ksmem[2 * tid] + ksmem[2 * tid + 1];
}

// reduce partials -> KVT [bh][80 rows][128 f] bf16 (row 64 = Ksum, 65..79 = 0)
__global__ __launch_bounds__(256) void kv_reduce_kernel(
    const float* __restrict__ partial, u16* __restrict__ KVT) {
  const int bh = blockIdx.x, tid = threadIdx.x;
  for (int e = tid; e < 8320; e += 256) {
    float s = 0.f;
#pragma unroll
    for (int c = 0; c < 16; ++c) s += partial[(size_t)(bh * 16 + c) * 8320 + e];
    int f = e / 65, col = e % 65;
    KVT[((size_t)bh * 80 + col) * 128 + f] = f2bf(s);
  }
  for (int i = tid; i < 15 * 128; i += 256)
    KVT[((size_t)bh * 80 + 65) * 128 + i] = 0;
}

// ---------------- QKV = Qp @ KV, Z via 5th N-frag, divide -> A bf16 ----------------
__global__ __launch_bounds__(256) void qkv_div_kernel(
    const u16* __restrict__ Qp, const u16* __restrict__ KVT, u16* __restrict__ A) {
  __shared__ u16 smem2[26624];
  u16* Qs = smem2;          // [128 s][128 f]
  u16* Ks = smem2 + 16384;  // [80 rows][128 f]
  const int tid = threadIdx.x, lane = tid & 63, wave = tid >> 6;
  const int bh = blockIdx.x >> 6, st = blockIdx.x & 63;

  stage_r256<128>((const uint8_t*)(Qp + ((size_t)bh * 8192 + st * 128) * 128), 256,
                  Qs, wave, lane);
  stage_r256<80>((const uint8_t*)(KVT + (size_t)bh * 80 * 128), 256, Ks, wave, lane);
  __syncthreads();

  f32x4 acc[2][5];
#pragma unroll
  for (int m = 0; m < 2; ++m)
#pragma unroll
    for (int n = 0; n < 5; ++n) acc[m][n] = (f32x4){0.f, 0.f, 0.f, 0.f};

#pragma unroll
  for (int kk = 0; kk < 4; ++kk) {
    const int ko = kk * 32 + (lane >> 4) * 8;
    bf16x8 a[2], bb[5];
#pragma unroll
    for (int m = 0; m < 2; ++m)
      a[m] = *(const bf16x8*)&Qs[(size_t)(wave * 32 + m * 16 + (lane & 15)) * 128 + ko];
#pragma unroll
    for (int n = 0; n < 5; ++n)
      bb[n] = *(const bf16x8*)&Ks[(size_t)(n * 16 + (lane & 15)) * 128 + ko];
#pragma unroll
    for (int m = 0; m < 2; ++m)
#pragma unroll
      for (int n = 0; n < 5; ++n)
        acc[m][n] = __builtin_amdgcn_mfma_f32_16x16x32_bf16(a[m], bb[n], acc[m][n], 0, 0, 0);
  }

  const int b_ = bh >> 4, h = bh & 15;
#pragma unroll
  for (int m = 0; m < 2; ++m) {
#pragma unroll
    for (int r = 0; r < 4; ++r) {
      float z = fmaxf(__shfl(acc[m][4][r], lane & 48), 1e-6f);
      int srow = st * 128 + wave * 32 + m * 16 + (lane >> 4) * 4 + r;
      size_t rowb = ((size_t)b_ * 8192 + srow) * 1024 + h * 64;
#pragma unroll
      for (int n = 0; n < 4; ++n)
        A[rowb + n * 16 + (lane & 15)] = f2bf(acc[m][n][r] / z);
    }
  }
}

// ---------------- out = A @ Wo (fp32 out), 128^2 ----------------
__global__ __launch_bounds__(256, 3) void gemm_out_kernel(
    const u16* __restrict__ A, const u16* __restrict__ WoT, float* __restrict__ out) {
  __shared__ u16 smem[16384];
  u16* As = smem;
  u16* Bs = smem + 8192;
  const int tid = threadIdx.x, lane = tid & 63, wave = tid >> 6;
  const int wr = wave >> 1, wc = wave & 1;
  const int nb = (blockIdx.x & 7) * 256 + (blockIdx.x >> 3);
  const int tn = nb & 7, tm = nb >> 3;

  f32x4 acc[4][4];
#pragma unroll
  for (int m = 0; m < 4; ++m)
#pragma unroll
    for (int n = 0; n < 4; ++n) acc[m][n] = (f32x4){0.f, 0.f, 0.f, 0.f};

  const uint8_t* aB = (const uint8_t*)(A + (size_t)tm * 128 * 1024);
  const uint8_t* bB = (const uint8_t*)(WoT + (size_t)tn * 128 * 1024);
  for (int kt = 0; kt < 16; ++kt) {
    stage128_sw(aB + kt * 128, 2048, As, wave, lane);
    stage128_sw(bB + kt * 128, 2048, Bs, wave, lane);
    __syncthreads();
    mma128_sw(As, Bs, acc, wr, wc, lane);
    __syncthreads();
  }

  const int rowbase = tm * 128 + wr * 64;
  const int colbase = tn * 128 + wc * 64;
#pragma unroll
  for (int m = 0; m < 4; ++m)
#pragma unroll
    for (int n = 0; n < 4; ++n) {
      int col = colbase + n * 16 + (lane & 15);
      int row = rowbase + m * 16 + (lane >> 4) * 4;
#pragma unroll
      for (int r = 0; r < 4; ++r)
        out[(size_t)(row + r) * 1024 + col] = acc[m][n][r];
    }
}

// ---------------- host ----------------

extern "C" void kernel_launch(void* const* d_in, const int* in_sizes, int n_in,
                              void* d_out, int out_size, void* d_ws, size_t ws_size,
                              hipStream_t stream) {
  const float* x  = (const float*)d_in[0];
  const float* Wq = (const float*)d_in[1];
  const float* Wk = (const float*)d_in[2];
  const float* Wv = (const float*)d_in[3];
  const float* Wo = (const float*)d_in[4];
  const float* rf = (const float*)d_in[5];
  float* out = (float*)d_out;

  if (ws_size < (size_t)411058176) return;   // fail cleanly, don't fault

  u16* ws = (u16*)d_ws;
  u16* xb    = ws;
  u16* Qp    = ws + 33554432UL;
  u16* KpT   = ws + 100663296UL;
  u16* VhT   = ws + 167772160UL;
  u16* wqkvT = ws + 201326592UL;
  u16* woT   = ws + 204472320UL;
  u16* rfT   = ws + 205520896UL;
  float* partial = (float*)xb;          // [1024][128][65] f32 (34 MB), alias xb
  u16* KVT   = wqkvT;                   // [64][80][128] bf16, alias wqkvT (dead)
  u16* Abuf  = xb;                      // [32768][1024] bf16, alias xb

  cast_x_kernel<<<4096, 256, 0, stream>>>(x, xb, 8388608L);
  transpose_cast_kernel<<<1024, 256, 0, stream>>>(Wq, wqkvT,            1024, 1024);
  transpose_cast_kernel<<<1024, 256, 0, stream>>>(Wk, wqkvT + 1048576,  1024, 1024);
  transpose_cast_kernel<<<1024, 256, 0, stream>>>(Wv, wqkvT + 2097152,  1024, 1024);
  transpose_cast_kernel<<<1024, 256, 0, stream>>>(Wo, woT,              1024, 1024);
  transpose_cast_kernel<<<8,    256, 0, stream>>>(rf, rfT,              64,   128);

  gemm_qkv_phi_kernel<<<1536, 512, 0, stream>>>(xb, wqkvT, rfT, Qp, KpT, VhT);
  kv_partial_kernel<<<1024, 256, 0, stream>>>(KpT, VhT, partial);
  kv_reduce_kernel<<<64, 256, 0, stream>>>(partial, KVT);
  qkv_div_kernel<<<4096, 256, 0, stream>>>(Qp, KVT, Abuf);
  gemm_out_kernel<<<2048, 256, 0, stream>>>(Abuf, woT, out);
}

// Round 9
// 607.689 us; speedup vs baseline: 1.0423x; 1.0423x over previous
//
#include <hip/hip_runtime.h>
#include <stdint.h>

// LinearSelfAttention: out = ((phi(xWq) @ (phi(xWk)^T V)) / Z) @ Wo
// B=4 S=8192 H=16 Dh=64 F=128 Dm=1024. All GEMMs bf16-MFMA/fp32-acc.
// R9: 128^2 tile (3 blocks/CU, R4 occupancy) + BK=32 3-slot counted-vmcnt
//     pipeline (T4; loads never drain mid-loop). Row-dependent rotation
//     swizzle (uniform 8 lanes/bank-group). Epilogue = R4's proven phi path.

#define DEVINL __device__ __forceinline__

typedef float f32x4 __attribute__((ext_vector_type(4)));
typedef __bf16 bf16x8 __attribute__((ext_vector_type(8)));
typedef unsigned short u16;

#define TSTR 136   // epilogue tile row stride (u16)
#define RSTR 72    // rf row stride (u16)

DEVINL u16 f2bf(float f) {
  union { float f; uint32_t u; } v; v.f = f;
  uint32_t u = v.u;
  u += 0x7fffu + ((u >> 16) & 1u);   // round-to-nearest-even
  return (u16)(u >> 16);
}
DEVINL float bf2f(u16 h) {
  union { uint32_t u; float f; } v; v.u = ((uint32_t)h) << 16;
  return v.f;
}

#define GLOAD16(gp, lp) __builtin_amdgcn_global_load_lds( \
    (const __attribute__((address_space(1))) unsigned int*)(gp), \
    (__attribute__((address_space(3))) unsigned int*)(lp), 16, 0, 0)

// ---- linear staging (kv_partial / qkv_div) ----
template <int ROWS>
DEVINL void stage_r128(const uint8_t* g, size_t stride, u16* lds, int wave, int lane) {
#pragma unroll
  for (int j = 0; j < ROWS / 32; ++j) {
    int row = wave * (ROWS / 4) + j * 8 + (lane >> 3);
    GLOAD16(g + (size_t)row * stride + (size_t)(lane & 7) * 16,
            (uint8_t*)lds + (size_t)(wave * (ROWS / 4) + j * 8) * 128);
  }
}
template <int ROWS>
DEVINL void stage_r256(const uint8_t* g, size_t stride, u16* lds, int wave, int lane) {
#pragma unroll
  for (int j = 0; j < ROWS / 16; ++j) {
    int row = wave * (ROWS / 4) + j * 4 + (lane >> 4);
    GLOAD16(g + (size_t)row * stride + (size_t)(lane & 15) * 16,
            (uint8_t*)lds + (size_t)(wave * (ROWS / 4) + j * 4) * 256);
  }
}

// ---- BK=32 slot: A[128][32] + B[128][32] bf16 = 16 KiB.
// LDS[row][sl] holds global chunk (sl - (row>>1)) & 3  (16B chunks, 4/row).
// 4 gload_lds per thread per slot. Source row stride = 2048 B (K=1024 bf16).
DEVINL void stage_slot32(const u16* gA, const u16* gB, u16* slot, int kt, int tid) {
  const int koff = kt * 64;
#pragma unroll
  for (int l = 0; l < 2; ++l) {
    int ia = l * 256 + tid;
    int ra = ia >> 2, sa = ia & 3;
    int ca = (sa - (ra >> 1)) & 3;
    GLOAD16((const uint8_t*)gA + (size_t)ra * 2048 + koff + ca * 16,
            (uint8_t*)slot + (size_t)(ia & ~63) * 16);
    int rb = ra, sb = sa;
    int cb = ca;
    GLOAD16((const uint8_t*)gB + (size_t)rb * 2048 + koff + cb * 16,
            (uint8_t*)(slot + 4096) + (size_t)(ia & ~63) * 16);
  }
}

DEVINL bf16x8 frd32(const u16* base, int row, int c0) {
  int cp = (c0 + (row >> 1)) & 3;
  return *(const bf16x8*)&base[(size_t)row * 32 + cp * 8];
}

// counted-vmcnt 128^2 main loop: 32 K-tiles of 32, 3 slots, 2-deep prefetch.
DEVINL void gemm_main32(const u16* gA, const u16* gB, u16* smem,
                        f32x4 acc[4][4], int tid, int lane, int wr, int wc) {
  stage_slot32(gA, gB, smem, 0, tid);
  stage_slot32(gA, gB, smem + 8192, 1, tid);
  const int c0 = lane >> 4;
  int slot_idx = 0;
  for (int t = 0; t < 32; ++t) {
    u16* sl = smem + slot_idx * 8192;
    if (t < 30) {
      int nxt = slot_idx + 2; if (nxt >= 3) nxt -= 3;
      stage_slot32(gA, gB, smem + nxt * 8192, t + 2, tid);
      asm volatile("s_waitcnt vmcnt(8)" ::: "memory");
    } else if (t == 30) {
      asm volatile("s_waitcnt vmcnt(4)" ::: "memory");
    } else {
      asm volatile("s_waitcnt vmcnt(0)" ::: "memory");
    }
    __builtin_amdgcn_s_barrier();
    asm volatile("" ::: "memory");
    bf16x8 a[4], b[4];
#pragma unroll
    for (int m = 0; m < 4; ++m)
      a[m] = frd32(sl, wr * 64 + m * 16 + (lane & 15), c0);
#pragma unroll
    for (int n = 0; n < 4; ++n)
      b[n] = frd32(sl + 4096, wc * 64 + n * 16 + (lane & 15), c0);
    __builtin_amdgcn_s_setprio(1);
#pragma unroll
    for (int m = 0; m < 4; ++m)
#pragma unroll
      for (int n = 0; n < 4; ++n)
        acc[m][n] = __builtin_amdgcn_mfma_f32_16x16x32_bf16(a[m], b[n], acc[m][n], 0, 0, 0);
    __builtin_amdgcn_s_setprio(0);
    __builtin_amdgcn_s_barrier();
    asm volatile("" ::: "memory");
    if (++slot_idx == 3) slot_idx = 0;
  }
}

// ---------------- prep kernels ----------------

__global__ __launch_bounds__(256) void cast_x_kernel(
    const float* __restrict__ src, u16* __restrict__ dst, long n4) {
  long i = (long)blockIdx.x * 256 + threadIdx.x;
  const long stride = (long)gridDim.x * 256;
  const float4* s4 = (const float4*)src;
  uint2* d4 = (uint2*)dst;
  for (; i < n4; i += stride) {
    float4 v = s4[i];
    uint2 o;
    o.x = (uint32_t)f2bf(v.x) | ((uint32_t)f2bf(v.y) << 16);
    o.y = (uint32_t)f2bf(v.z) | ((uint32_t)f2bf(v.w) << 16);
    d4[i] = o;
  }
}

// src fp32 [R][C] -> dst bf16 [C][R]
__global__ __launch_bounds__(256) void transpose_cast_kernel(
    const float* __restrict__ src, u16* __restrict__ dst, int R, int C) {
  __shared__ float tile[32 * 33];
  const int ntr = R >> 5;
  const int tr = blockIdx.x % ntr, tc = blockIdx.x / ntr;
  const int tid = threadIdx.x;
  {
    int r = tid >> 3, c4 = (tid & 7) * 4;
    float4 v = *(const float4*)&src[(size_t)(tr * 32 + r) * C + tc * 32 + c4];
    tile[r * 33 + c4 + 0] = v.x;
    tile[r * 33 + c4 + 1] = v.y;
    tile[r * 33 + c4 + 2] = v.z;
    tile[r * 33 + c4 + 3] = v.w;
  }
  __syncthreads();
  {
    int c = tid >> 3, r4 = (tid & 7) * 4;
    uint2 o;
    o.x = (uint32_t)f2bf(tile[(r4 + 0) * 33 + c]) |
          ((uint32_t)f2bf(tile[(r4 + 1) * 33 + c]) << 16);
    o.y = (uint32_t)f2bf(tile[(r4 + 2) * 33 + c]) |
          ((uint32_t)f2bf(tile[(r4 + 3) * 33 + c]) << 16);
    *(uint2*)&dst[(size_t)(tc * 32 + c) * R + tr * 32 + r4] = o;
  }
}

// ---------------- QKV GEMM (N = 3 x 1024) + fused phi ----------------
__global__ __launch_bounds__(256, 3) void gemm_qkv_phi_kernel(
    const u16* __restrict__ xb, const u16* __restrict__ wT,
    const u16* __restrict__ rfT,
    u16* __restrict__ Qp, u16* __restrict__ KpT, u16* __restrict__ VhT) {
  __shared__ u16 smem[26624];   // 52 KiB: slots 0..24575; epi TILE 0..17407, Rs 17408..
  u16* Rs = smem + 17408;
  const int tid = threadIdx.x, lane = tid & 63, wave = tid >> 6;
  const int wr = wave >> 1, wc = wave & 1;
  const int nb = (blockIdx.x & 7) * 768 + (blockIdx.x >> 3);   // XCD-bijective
  const int tn = nb % 24, tm = nb / 24;
  const int tensor = tn >> 3;

  f32x4 acc[4][4];
#pragma unroll
  for (int m = 0; m < 4; ++m)
#pragma unroll
    for (int n = 0; n < 4; ++n) acc[m][n] = (f32x4){0.f, 0.f, 0.f, 0.f};

  gemm_main32(xb + (size_t)tm * 128 * 1024, wT + (size_t)tn * 128 * 1024,
              smem, acc, tid, lane, wr, wc);

  const int b = (tm * 128) >> 13;
  const int sblk = (tm * 128) & 8191;

  if (tensor == 2) {
    // V: transpose 128x128 tile via padded TILE, coalesced 16B rows out.
#pragma unroll
    for (int m = 0; m < 4; ++m) {
      int sl = wr * 64 + m * 16 + (lane >> 4) * 4;
#pragma unroll
      for (int n = 0; n < 4; ++n) {
        int cl = wc * 64 + n * 16 + (lane & 15);
#pragma unroll
        for (int r = 0; r < 4; ++r) smem[cl * TSTR + sl + r] = f2bf(acc[m][n][r]);
      }
    }
    __syncthreads();
#pragma unroll
    for (int it = 0; it < 8; ++it) {
      int cl = it * 16 + (tid >> 4);
      int c = (tn & 7) * 128 + cl;
      int h = c >> 6, d = c & 63;
      size_t off = ((size_t)((b * 16 + h) * 64 + d)) * 8192 + sblk + (tid & 15) * 8;
      *(uint4*)&VhT[off] = *(const uint4*)&smem[cl * TSTR + (tid & 15) * 8];
    }
    return;
  }

  // ---- Q/K: fused phi ----
  // 1) dump bf16 GEMM tile into TILE [128 s][TSTR]; load rf into padded Rs
#pragma unroll
  for (int m = 0; m < 4; ++m) {
    int sl = wr * 64 + m * 16 + (lane >> 4) * 4;
#pragma unroll
    for (int n = 0; n < 4; ++n) {
      int cl = wc * 64 + n * 16 + (lane & 15);
#pragma unroll
      for (int r = 0; r < 4; ++r) smem[(sl + r) * TSTR + cl] = f2bf(acc[m][n][r]);
    }
  }
#pragma unroll
  for (int p4 = 0; p4 < 4; ++p4) {
    int idx = p4 * 256 + tid;
    int f = idx >> 3, c = idx & 7;
    *(uint4*)&Rs[f * RSTR + c * 8] = *(const uint4*)&rfT[f * 64 + c * 8];
  }
  __syncthreads();

  // 2) preload a-frags for BOTH heads (TILE reusable after)
  bf16x8 afr[2][2][2];   // [hh][kk][m]
#pragma unroll
  for (int hh = 0; hh < 2; ++hh)
#pragma unroll
    for (int kk = 0; kk < 2; ++kk) {
      const int ko = kk * 32 + (lane >> 4) * 8;
#pragma unroll
      for (int m = 0; m < 2; ++m)
        afr[hh][kk][m] = *(const bf16x8*)&smem[
            (size_t)(wave * 32 + m * 16 + (lane & 15)) * TSTR + hh * 64 + ko];
    }
  __syncthreads();

  const float SC = 0.088388347648318447f;  // 128^-0.5
#pragma unroll
  for (int hh = 0; hh < 2; ++hh) {
    const int h = (tn & 7) * 2 + hh;
    f32x4 p[2][8];
#pragma unroll
    for (int m = 0; m < 2; ++m)
#pragma unroll
      for (int n = 0; n < 8; ++n) p[m][n] = (f32x4){0.f, 0.f, 0.f, 0.f};
#pragma unroll
    for (int kk = 0; kk < 2; ++kk) {
      const int ko = kk * 32 + (lane >> 4) * 8;
      bf16x8 bb[8];
#pragma unroll
      for (int n = 0; n < 8; ++n)
        bb[n] = *(const bf16x8*)&Rs[(size_t)(n * 16 + (lane & 15)) * RSTR + ko];
#pragma unroll
      for (int m = 0; m < 2; ++m)
#pragma unroll
        for (int n = 0; n < 8; ++n)
          p[m][n] = __builtin_amdgcn_mfma_f32_16x16x32_bf16(afr[hh][kk][m], bb[n], p[m][n], 0, 0, 0);
    }

    if (tensor == 0) {
      // Q: phi -> TILE [s][TSTR] -> coalesced row stores
#pragma unroll
      for (int m = 0; m < 2; ++m)
#pragma unroll
        for (int n = 0; n < 8; ++n) {
          int f = n * 16 + (lane & 15);
          int sl = wave * 32 + m * 16 + (lane >> 4) * 4;
#pragma unroll
          for (int r = 0; r < 4; ++r) {
            float v = ((n < 4) ? __cosf(p[m][n][r]) : __sinf(p[m][n][r])) * SC;
            smem[(sl + r) * TSTR + f] = f2bf(v);
          }
        }
      __syncthreads();
      const size_t base_bh = (size_t)(b * 16 + h) * 8192;
#pragma unroll
      for (int it = 0; it < 8; ++it) {
        int s = it * 16 + (tid >> 4);
        *(uint4*)&Qp[(base_bh + sblk + s) * 128 + (tid & 15) * 8] =
            *(const uint4*)&smem[s * TSTR + (tid & 15) * 8];
      }
    } else {
      // K: phi transposed -> TILE [f][TSTR] -> coalesced s-row stores
#pragma unroll
      for (int m = 0; m < 2; ++m)
#pragma unroll
        for (int n = 0; n < 8; ++n) {
          int f = n * 16 + (lane & 15);
          int sl = wave * 32 + m * 16 + (lane >> 4) * 4;
#pragma unroll
          for (int r = 0; r < 4; ++r) {
            float v = ((n < 4) ? __cosf(p[m][n][r]) : __sinf(p[m][n][r])) * SC;
            smem[f * TSTR + sl + r] = f2bf(v);
          }
        }
      __syncthreads();
#pragma unroll
      for (int it = 0; it < 8; ++it) {
        int f = it * 16 + (tid >> 4);
        *(uint4*)&KpT[((size_t)(b * 16 + h) * 128 + f) * 8192 + sblk + (tid & 15) * 8] =
            *(const uint4*)&smem[f * TSTR + (tid & 15) * 8];
      }
    }
    if (hh == 0) __syncthreads();   // stores done before overwriting TILE
  }
}

// ---------------- KV = Kp^T V + Ksum, 16 s-chunks ----------------
__global__ __launch_bounds__(256) void kv_partial_kernel(
    const u16* __restrict__ KpT, const u16* __restrict__ VhT,
    float* __restrict__ partial) {
  __shared__ u16 smem2[12288];
  __shared__ float ksmem[256];
  u16* As = smem2;        // [128 f][64 s]
  u16* Bs = smem2 + 8192; // [64 d][64 s]
  const int tid = threadIdx.x, lane = tid & 63, wave = tid >> 6;
  const int bh = blockIdx.x >> 4, ch = blockIdx.x & 15;
  const uint8_t* aB = (const uint8_t*)(KpT + (size_t)bh * 128 * 8192 + ch * 512);
  const uint8_t* bB = (const uint8_t*)(VhT + (size_t)bh * 64 * 8192 + ch * 512);

  f32x4 acc[2][4];
#pragma unroll
  for (int m = 0; m < 2; ++m)
#pragma unroll
    for (int n = 0; n < 4; ++n) acc[m][n] = (f32x4){0.f, 0.f, 0.f, 0.f};
  float ks = 0.f;
  const int fK = tid >> 1, sO = (tid & 1) * 32;

  for (int t = 0; t < 8; ++t) {
    stage_r128<128>(aB + t * 128, 16384, As, wave, lane);
    stage_r128<64>(bB + t * 128, 16384, Bs, wave, lane);
    __syncthreads();
#pragma unroll
    for (int i = 0; i < 4; ++i) {
      uint4 v = *(const uint4*)&As[fK * 64 + sO + i * 8];
      ks += bf2f((u16)(v.x & 0xffff)) + bf2f((u16)(v.x >> 16));
      ks += bf2f((u16)(v.y & 0xffff)) + bf2f((u16)(v.y >> 16));
      ks += bf2f((u16)(v.z & 0xffff)) + bf2f((u16)(v.z >> 16));
      ks += bf2f((u16)(v.w & 0xffff)) + bf2f((u16)(v.w >> 16));
    }
#pragma unroll
    for (int kk = 0; kk < 2; ++kk) {
      const int ko = kk * 32 + (lane >> 4) * 8;
      bf16x8 a[2], bb[4];
#pragma unroll
      for (int m = 0; m < 2; ++m)
        a[m] = *(const bf16x8*)&As[(size_t)(wave * 32 + m * 16 + (lane & 15)) * 64 + ko];
#pragma unroll
      for (int n = 0; n < 4; ++n)
        bb[n] = *(const bf16x8*)&Bs[(size_t)(n * 16 + (lane & 15)) * 64 + ko];
#pragma unroll
      for (int m = 0; m < 2; ++m)
#pragma unroll
        for (int n = 0; n < 4; ++n)
          acc[m][n] = __builtin_amdgcn_mfma_f32_16x16x32_bf16(a[m], bb[n], acc[m][n], 0, 0, 0);
    }
    __syncthreads();
  }

  float* pb = partial + (size_t)blockIdx.x * (128 * 65);
#pragma unroll
  for (int m = 0; m < 2; ++m)
#pragma unroll
    for (int n = 0; n < 4; ++n) {
      int d = n * 16 + (lane & 15);
#pragma unroll
      for (int r = 0; r < 4; ++r) {
        int f = wave * 32 + m * 16 + (lane >> 4) * 4 + r;
        pb[f * 65 + d] = acc[m][n][r];
      }
    }
  ksmem[tid] = ks;
  __syncthreads();
  if (tid < 128) pb[tid * 65 + 64] = ksmem[2 * tid] + ksmem[2 * tid + 1];
}

// reduce partials -> KVT [bh][80 rows][128 f] bf16 (row 64 = Ksum, 65..79 = 0)
__global__ __launch_bounds__(256) void kv_reduce_kernel(
    const float* __restrict__ partial, u16* __restrict__ KVT) {
  const int bh = blockIdx.x, tid = threadIdx.x;
  for (int e = tid; e < 8320; e += 256) {
    float s = 0.f;
#pragma unroll
    for (int c = 0; c < 16; ++c) s += partial[(size_t)(bh * 16 + c) * 8320 + e];
    int f = e / 65, col = e % 65;
    KVT[((size_t)bh * 80 + col) * 128 + f] = f2bf(s);
  }
  for (int i = tid; i < 15 * 128; i += 256)
    KVT[((size_t)bh * 80 + 65) * 128 + i] = 0;
}

// ---------------- QKV = Qp @ KV, Z via 5th N-frag, divide -> A bf16 ----------------
__global__ __launch_bounds__(256) void qkv_div_kernel(
    const u16* __restrict__ Qp, const u16* __restrict__ KVT, u16* __restrict__ A) {
  __shared__ u16 smem2[26624];
  u16* Qs = smem2;          // [128 s][128 f]
  u16* Ks = smem2 + 16384;  // [80 rows][128 f]
  const int tid = threadIdx.x, lane = tid & 63, wave = tid >> 6;
  const int bh = blockIdx.x >> 6, st = blockIdx.x & 63;

  stage_r256<128>((const uint8_t*)(Qp + ((size_t)bh * 8192 + st * 128) * 128), 256,
                  Qs, wave, lane);
  stage_r256<80>((const uint8_t*)(KVT + (size_t)bh * 80 * 128), 256, Ks, wave, lane);
  __syncthreads();

  f32x4 acc[2][5];
#pragma unroll
  for (int m = 0; m < 2; ++m)
#pragma unroll
    for (int n = 0; n < 5; ++n) acc[m][n] = (f32x4){0.f, 0.f, 0.f, 0.f};

#pragma unroll
  for (int kk = 0; kk < 4; ++kk) {
    const int ko = kk * 32 + (lane >> 4) * 8;
    bf16x8 a[2], bb[5];
#pragma unroll
    for (int m = 0; m < 2; ++m)
      a[m] = *(const bf16x8*)&Qs[(size_t)(wave * 32 + m * 16 + (lane & 15)) * 128 + ko];
#pragma unroll
    for (int n = 0; n < 5; ++n)
      bb[n] = *(const bf16x8*)&Ks[(size_t)(n * 16 + (lane & 15)) * 128 + ko];
#pragma unroll
    for (int m = 0; m < 2; ++m)
#pragma unroll
      for (int n = 0; n < 5; ++n)
        acc[m][n] = __builtin_amdgcn_mfma_f32_16x16x32_bf16(a[m], bb[n], acc[m][n], 0, 0, 0);
  }

  const int b_ = bh >> 4, h = bh & 15;
#pragma unroll
  for (int m = 0; m < 2; ++m) {
#pragma unroll
    for (int r = 0; r < 4; ++r) {
      float z = fmaxf(__shfl(acc[m][4][r], lane & 48), 1e-6f);
      int srow = st * 128 + wave * 32 + m * 16 + (lane >> 4) * 4 + r;
      size_t rowb = ((size_t)b_ * 8192 + srow) * 1024 + h * 64;
#pragma unroll
      for (int n = 0; n < 4; ++n)
        A[rowb + n * 16 + (lane & 15)] = f2bf(acc[m][n][r] / z);
    }
  }
}

// ---------------- out = A @ Wo (fp32 out), counted 128^2 ----------------
__global__ __launch_bounds__(256, 3) void gemm_out_kernel(
    const u16* __restrict__ A, const u16* __restrict__ WoT, float* __restrict__ out) {
  __shared__ u16 smem[24576];   // 48 KiB: 3 slots
  const int tid = threadIdx.x, lane = tid & 63, wave = tid >> 6;
  const int wr = wave >> 1, wc = wave & 1;
  const int nb = (blockIdx.x & 7) * 256 + (blockIdx.x >> 3);
  const int tn = nb & 7, tm = nb >> 3;

  f32x4 acc[4][4];
#pragma unroll
  for (int m = 0; m < 4; ++m)
#pragma unroll
    for (int n = 0; n < 4; ++n) acc[m][n] = (f32x4){0.f, 0.f, 0.f, 0.f};

  gemm_main32(A + (size_t)tm * 128 * 1024, WoT + (size_t)tn * 128 * 1024,
              smem, acc, tid, lane, wr, wc);

  const int rowbase = tm * 128 + wr * 64;
  const int colbase = tn * 128 + wc * 64;
#pragma unroll
  for (int m = 0; m < 4; ++m)
#pragma unroll
    for (int n = 0; n < 4; ++n) {
      int col = colbase + n * 16 + (lane & 15);
      int row = rowbase + m * 16 + (lane >> 4) * 4;
#pragma unroll
      for (int r = 0; r < 4; ++r)
        out[(size_t)(row + r) * 1024 + col] = acc[m][n][r];
    }
}

// ---------------- host ----------------

extern "C" void kernel_launch(void* const* d_in, const int* in_sizes, int n_in,
                              void* d_out, int out_size, void* d_ws, size_t ws_size,
                              hipStream_t stream) {
  const float* x  = (const float*)d_in[0];
  const float* Wq = (const float*)d_in[1];
  const float* Wk = (const float*)d_in[2];
  const float* Wv = (const float*)d_in[3];
  const float* Wo = (const float*)d_in[4];
  const float* rf = (const float*)d_in[5];
  float* out = (float*)d_out;

  if (ws_size < (size_t)411058176) return;   // fail cleanly, don't fault

  u16* ws = (u16*)d_ws;
  u16* xb    = ws;
  u16* Qp    = ws + 33554432UL;
  u16* KpT   = ws + 100663296UL;
  u16* VhT   = ws + 167772160UL;
  u16* wqkvT = ws + 201326592UL;
  u16* woT   = ws + 204472320UL;
  u16* rfT   = ws + 205520896UL;
  float* partial = (float*)xb;          // [1024][128][65] f32 (34 MB), alias xb
  u16* KVT   = wqkvT;                   // [64][80][128] bf16, alias wqkvT (dead)
  u16* Abuf  = xb;                      // [32768][1024] bf16, alias xb

  cast_x_kernel<<<4096, 256, 0, stream>>>(x, xb, 8388608L);
  transpose_cast_kernel<<<1024, 256, 0, stream>>>(Wq, wqkvT,            1024, 1024);
  transpose_cast_kernel<<<1024, 256, 0, stream>>>(Wk, wqkvT + 1048576,  1024, 1024);
  transpose_cast_kernel<<<1024, 256, 0, stream>>>(Wv, wqkvT + 2097152,  1024, 1024);
  transpose_cast_kernel<<<1024, 256, 0, stream>>>(Wo, woT,              1024, 1024);
  transpose_cast_kernel<<<8,    256, 0, stream>>>(rf, rfT,              64,   128);

  gemm_qkv_phi_kernel<<<6144, 256, 0, stream>>>(xb, wqkvT, rfT, Qp, KpT, VhT);
  kv_partial_kernel<<<1024, 256, 0, stream>>>(KpT, VhT, partial);
  kv_reduce_kernel<<<64, 256, 0, stream>>>(partial, KVT);
  qkv_div_kernel<<<4096, 256, 0, stream>>>(Qp, KVT, Abuf);
  gemm_out_kernel<<<2048, 256, 0, stream>>>(Abuf, woT, out);
}

// Round 10
// 542.093 us; speedup vs baseline: 1.1684x; 1.1210x over previous
//
#include <hip/hip_runtime.h>
#include <stdint.h>

// LinearSelfAttention: out = ((phi(xWq) @ (phi(xWk)^T V)) / Z) @ Wo
// B=4 S=8192 H=16 Dh=64 F=128 Dm=1024. All GEMMs bf16-MFMA/fp32-acc.
// R10: exact R4 GEMM structure (proven 317 us, = documented 2-phase K=1024
//      ceiling) + L2 super-tile blocking (8tm x 8tn = 4 MB working set per
//      XCD L2; was 6 MB B thrash -> FETCH 709 MB). kv_partial 16-chunk.

#define DEVINL __device__ __forceinline__

typedef float f32x4 __attribute__((ext_vector_type(4)));
typedef __bf16 bf16x8 __attribute__((ext_vector_type(8)));
typedef unsigned short u16;

#define TSTR 136   // epilogue tile row stride (u16): 272B, 16B-aligned
#define RSTR 72    // rf row stride (u16): 144B, 16B-aligned

DEVINL u16 f2bf(float f) {
  union { float f; uint32_t u; } v; v.f = f;
  uint32_t u = v.u;
  u += 0x7fffu + ((u >> 16) & 1u);   // round-to-nearest-even
  return (u16)(u >> 16);
}
DEVINL float bf2f(u16 h) {
  union { uint32_t u; float f; } v; v.u = ((uint32_t)h) << 16;
  return v.f;
}

#define GLOAD16(gp, lp) __builtin_amdgcn_global_load_lds( \
    (const __attribute__((address_space(1))) unsigned int*)(gp), \
    (__attribute__((address_space(3))) unsigned int*)(lp), 16, 0, 0)

// ---- linear staging (kv_partial / qkv_div) ----
template <int ROWS>
DEVINL void stage_r128(const uint8_t* g, size_t stride, u16* lds, int wave, int lane) {
#pragma unroll
  for (int j = 0; j < ROWS / 32; ++j) {
    int row = wave * (ROWS / 4) + j * 8 + (lane >> 3);
    GLOAD16(g + (size_t)row * stride + (size_t)(lane & 7) * 16,
            (uint8_t*)lds + (size_t)(wave * (ROWS / 4) + j * 8) * 128);
  }
}
template <int ROWS>
DEVINL void stage_r256(const uint8_t* g, size_t stride, u16* lds, int wave, int lane) {
#pragma unroll
  for (int j = 0; j < ROWS / 16; ++j) {
    int row = wave * (ROWS / 4) + j * 4 + (lane >> 4);
    GLOAD16(g + (size_t)row * stride + (size_t)(lane & 15) * 16,
            (uint8_t*)lds + (size_t)(wave * (ROWS / 4) + j * 4) * 256);
  }
}

// ---- swizzled staging: LDS[row][c] holds global[row][c ^ (row&7)] ----
DEVINL void stage128_sw(const uint8_t* g, size_t stride, u16* lds, int wave, int lane) {
  const int c = (lane & 7) ^ (lane >> 3);   // row&7 == lane>>3
#pragma unroll
  for (int j = 0; j < 4; ++j) {
    int row = wave * 32 + j * 8 + (lane >> 3);
    GLOAD16(g + (size_t)row * stride + (size_t)c * 16,
            (uint8_t*)lds + (size_t)(wave * 32 + j * 8) * 128);
  }
}

// 128x128 tile, BK=64, 4 waves 2x2, 4x4 frags; SWIZZLED LDS reads.
DEVINL void mma128_sw(const u16* As, const u16* Bs, f32x4 acc[4][4],
                      int wr, int wc, int lane) {
#pragma unroll
  for (int kk = 0; kk < 2; ++kk) {
    const int cw = kk * 4 + (lane >> 4);     // 16B-chunk index 0..7
    const int sw = (cw ^ (lane & 7)) * 8;    // row&7 == lane&7 for frag rows
    bf16x8 a[4], b[4];
#pragma unroll
    for (int m = 0; m < 4; ++m)
      a[m] = *(const bf16x8*)&As[(size_t)(wr * 64 + m * 16 + (lane & 15)) * 64 + sw];
#pragma unroll
    for (int n = 0; n < 4; ++n)
      b[n] = *(const bf16x8*)&Bs[(size_t)(wc * 64 + n * 16 + (lane & 15)) * 64 + sw];
#pragma unroll
    for (int m = 0; m < 4; ++m)
#pragma unroll
      for (int n = 0; n < 4; ++n)
        acc[m][n] = __builtin_amdgcn_mfma_f32_16x16x32_bf16(a[m], b[n], acc[m][n], 0, 0, 0);
  }
}

// ---------------- prep kernels ----------------

__global__ __launch_bounds__(256) void cast_x_kernel(
    const float* __restrict__ src, u16* __restrict__ dst, long n4) {
  long i = (long)blockIdx.x * 256 + threadIdx.x;
  const long stride = (long)gridDim.x * 256;
  const float4* s4 = (const float4*)src;
  uint2* d4 = (uint2*)dst;
  for (; i < n4; i += stride) {
    float4 v = s4[i];
    uint2 o;
    o.x = (uint32_t)f2bf(v.x) | ((uint32_t)f2bf(v.y) << 16);
    o.y = (uint32_t)f2bf(v.z) | ((uint32_t)f2bf(v.w) << 16);
    d4[i] = o;
  }
}

// src fp32 [R][C] -> dst bf16 [C][R]
__global__ __launch_bounds__(256) void transpose_cast_kernel(
    const float* __restrict__ src, u16* __restrict__ dst, int R, int C) {
  __shared__ float tile[32 * 33];
  const int ntr = R >> 5;
  const int tr = blockIdx.x % ntr, tc = blockIdx.x / ntr;
  const int tid = threadIdx.x;
  {
    int r = tid >> 3, c4 = (tid & 7) * 4;
    float4 v = *(const float4*)&src[(size_t)(tr * 32 + r) * C + tc * 32 + c4];
    tile[r * 33 + c4 + 0] = v.x;
    tile[r * 33 + c4 + 1] = v.y;
    tile[r * 33 + c4 + 2] = v.z;
    tile[r * 33 + c4 + 3] = v.w;
  }
  __syncthreads();
  {
    int c = tid >> 3, r4 = (tid & 7) * 4;
    uint2 o;
    o.x = (uint32_t)f2bf(tile[(r4 + 0) * 33 + c]) |
          ((uint32_t)f2bf(tile[(r4 + 1) * 33 + c]) << 16);
    o.y = (uint32_t)f2bf(tile[(r4 + 2) * 33 + c]) |
          ((uint32_t)f2bf(tile[(r4 + 3) * 33 + c]) << 16);
    *(uint2*)&dst[(size_t)(tc * 32 + c) * R + tr * 32 + r4] = o;
  }
}

// ---------------- QKV GEMM (N = 3 x 1024) + fused phi ----------------
// tn 0..7 : Q -> phi -> Qp [b,h,s,128]; tn 8..15: K -> phi -> KpT [b,h,128,s];
// tn 16..23: V -> VhT [b,h,d,s].
__global__ __launch_bounds__(256, 3) void gemm_qkv_phi_kernel(
    const u16* __restrict__ xb, const u16* __restrict__ wT,
    const u16* __restrict__ rfT,
    u16* __restrict__ Qp, u16* __restrict__ KpT, u16* __restrict__ VhT) {
  __shared__ u16 smem[26624];               // 52 KiB
  u16* As = smem;                           // [128][64] swizzled
  u16* Bs = smem + 8192;                    // [128][64] swizzled
  u16* Rs = smem + 17408;                   // [128 f][RSTR] (epilogue only)
  const int tid = threadIdx.x, lane = tid & 63, wave = tid >> 6;
  const int wr = wave >> 1, wc = wave & 1;
  // XCD-bijective + L2 super-tile blocking: per XCD, groups of 8tm x 8tn
  // (A-octet 2MB + B-octet 2MB = 4MB = one XCD L2). 6144 = 8 XCD * 768.
  const int xcd = blockIdx.x & 7;
  const int i = blockIdx.x >> 3;            // [0,768)
  const int g = i >> 6, j = i & 63;         // g in [0,12), j in [0,64)
  const int tn = (g % 3) * 8 + (j >> 3);
  const int tm = xcd * 32 + (g / 3) * 8 + (j & 7);
  const int tensor = tn >> 3;

  f32x4 acc[4][4];
#pragma unroll
  for (int m = 0; m < 4; ++m)
#pragma unroll
    for (int n = 0; n < 4; ++n) acc[m][n] = (f32x4){0.f, 0.f, 0.f, 0.f};

  const uint8_t* aB = (const uint8_t*)(xb + (size_t)tm * 128 * 1024);
  const uint8_t* bB = (const uint8_t*)(wT + (size_t)tn * 128 * 1024);
  for (int kt = 0; kt < 16; ++kt) {
    stage128_sw(aB + kt * 128, 2048, As, wave, lane);
    stage128_sw(bB + kt * 128, 2048, Bs, wave, lane);
    __syncthreads();
    mma128_sw(As, Bs, acc, wr, wc, lane);
    __syncthreads();
  }

  const int b = (tm * 128) >> 13;
  const int sblk = (tm * 128) & 8191;

  if (tensor == 2) {
    // V: transpose 128x128 tile via padded TILE, coalesced 16B rows out.
#pragma unroll
    for (int m = 0; m < 4; ++m) {
      int sl = wr * 64 + m * 16 + (lane >> 4) * 4;
#pragma unroll
      for (int n = 0; n < 4; ++n) {
        int cl = wc * 64 + n * 16 + (lane & 15);
#pragma unroll
        for (int r = 0; r < 4; ++r) smem[cl * TSTR + sl + r] = f2bf(acc[m][n][r]);
      }
    }
    __syncthreads();
#pragma unroll
    for (int it = 0; it < 8; ++it) {
      int cl = it * 16 + (tid >> 4);
      int c = (tn & 7) * 128 + cl;
      int h = c >> 6, d = c & 63;
      size_t off = ((size_t)((b * 16 + h) * 64 + d)) * 8192 + sblk + (tid & 15) * 8;
      *(uint4*)&VhT[off] = *(const uint4*)&smem[cl * TSTR + (tid & 15) * 8];
    }
    return;
  }

  // ---- Q/K: fused phi ----
  // 1) dump bf16 GEMM tile into TILE [128 s][TSTR]; stage rf into padded Rs
#pragma unroll
  for (int m = 0; m < 4; ++m) {
    int sl = wr * 64 + m * 16 + (lane >> 4) * 4;
#pragma unroll
    for (int n = 0; n < 4; ++n) {
      int cl = wc * 64 + n * 16 + (lane & 15);
#pragma unroll
      for (int r = 0; r < 4; ++r) smem[(sl + r) * TSTR + cl] = f2bf(acc[m][n][r]);
    }
  }
#pragma unroll
  for (int p4 = 0; p4 < 4; ++p4) {
    int idx = p4 * 256 + tid;
    int f = idx >> 3, c = idx & 7;
    *(uint4*)&Rs[f * RSTR + c * 8] = *(const uint4*)&rfT[f * 64 + c * 8];
  }
  __syncthreads();

  // 2) preload a-frags for BOTH heads (TILE reusable after)
  bf16x8 afr[2][2][2];   // [hh][kk][m]
#pragma unroll
  for (int hh = 0; hh < 2; ++hh)
#pragma unroll
    for (int kk = 0; kk < 2; ++kk) {
      const int ko = kk * 32 + (lane >> 4) * 8;
#pragma unroll
      for (int m = 0; m < 2; ++m)
        afr[hh][kk][m] = *(const bf16x8*)&smem[
            (size_t)(wave * 32 + m * 16 + (lane & 15)) * TSTR + hh * 64 + ko];
    }
  __syncthreads();

  const float SC = 0.088388347648318447f;  // 128^-0.5
#pragma unroll
  for (int hh = 0; hh < 2; ++hh) {
    const int h = (tn & 7) * 2 + hh;
    f32x4 p[2][8];
#pragma unroll
    for (int m = 0; m < 2; ++m)
#pragma unroll
      for (int n = 0; n < 8; ++n) p[m][n] = (f32x4){0.f, 0.f, 0.f, 0.f};
#pragma unroll
    for (int kk = 0; kk < 2; ++kk) {
      const int ko = kk * 32 + (lane >> 4) * 8;
      bf16x8 bb[8];
#pragma unroll
      for (int n = 0; n < 8; ++n)
        bb[n] = *(const bf16x8*)&Rs[(size_t)(n * 16 + (lane & 15)) * RSTR + ko];
#pragma unroll
      for (int m = 0; m < 2; ++m)
#pragma unroll
        for (int n = 0; n < 8; ++n)
          p[m][n] = __builtin_amdgcn_mfma_f32_16x16x32_bf16(afr[hh][kk][m], bb[n], p[m][n], 0, 0, 0);
    }

    if (tensor == 0) {
      // Q: phi -> TILE [s][TSTR] -> coalesced row stores
#pragma unroll
      for (int m = 0; m < 2; ++m)
#pragma unroll
        for (int n = 0; n < 8; ++n) {
          int f = n * 16 + (lane & 15);
          int sl = wave * 32 + m * 16 + (lane >> 4) * 4;
#pragma unroll
          for (int r = 0; r < 4; ++r) {
            float v = ((n < 4) ? __cosf(p[m][n][r]) : __sinf(p[m][n][r])) * SC;
            smem[(sl + r) * TSTR + f] = f2bf(v);
          }
        }
      __syncthreads();
      const size_t base_bh = (size_t)(b * 16 + h) * 8192;
#pragma unroll
      for (int it = 0; it < 8; ++it) {
        int s = it * 16 + (tid >> 4);
        *(uint4*)&Qp[(base_bh + sblk + s) * 128 + (tid & 15) * 8] =
            *(const uint4*)&smem[s * TSTR + (tid & 15) * 8];
      }
    } else {
      // K: phi transposed -> TILE [f][TSTR] -> coalesced s-row stores
#pragma unroll
      for (int m = 0; m < 2; ++m)
#pragma unroll
        for (int n = 0; n < 8; ++n) {
          int f = n * 16 + (lane & 15);
          int sl = wave * 32 + m * 16 + (lane >> 4) * 4;
#pragma unroll
          for (int r = 0; r < 4; ++r) {
            float v = ((n < 4) ? __cosf(p[m][n][r]) : __sinf(p[m][n][r])) * SC;
            smem[f * TSTR + sl + r] = f2bf(v);
          }
        }
      __syncthreads();
#pragma unroll
      for (int it = 0; it < 8; ++it) {
        int f = it * 16 + (tid >> 4);
        *(uint4*)&KpT[((size_t)(b * 16 + h) * 128 + f) * 8192 + sblk + (tid & 15) * 8] =
            *(const uint4*)&smem[f * TSTR + (tid & 15) * 8];
      }
    }
    if (hh == 0) __syncthreads();   // stores done before overwriting TILE
  }
}

// ---------------- KV = Kp^T V + Ksum, 16 s-chunks ----------------
__global__ __launch_bounds__(256) void kv_partial_kernel(
    const u16* __restrict__ KpT, const u16* __restrict__ VhT,
    float* __restrict__ partial) {
  __shared__ u16 smem2[12288];
  __shared__ float ksmem[256];
  u16* As = smem2;        // [128 f][64 s]
  u16* Bs = smem2 + 8192; // [64 d][64 s]
  const int tid = threadIdx.x, lane = tid & 63, wave = tid >> 6;
  const int bh = blockIdx.x >> 4, ch = blockIdx.x & 15;
  const uint8_t* aB = (const uint8_t*)(KpT + (size_t)bh * 128 * 8192 + ch * 512);
  const uint8_t* bB = (const uint8_t*)(VhT + (size_t)bh * 64 * 8192 + ch * 512);

  f32x4 acc[2][4];
#pragma unroll
  for (int m = 0; m < 2; ++m)
#pragma unroll
    for (int n = 0; n < 4; ++n) acc[m][n] = (f32x4){0.f, 0.f, 0.f, 0.f};
  float ks = 0.f;
  const int fK = tid >> 1, sO = (tid & 1) * 32;

  for (int t = 0; t < 8; ++t) {
    stage_r128<128>(aB + t * 128, 16384, As, wave, lane);
    stage_r128<64>(bB + t * 128, 16384, Bs, wave, lane);
    __syncthreads();
#pragma unroll
    for (int i = 0; i < 4; ++i) {
      uint4 v = *(const uint4*)&As[fK * 64 + sO + i * 8];
      ks += bf2f((u16)(v.x & 0xffff)) + bf2f((u16)(v.x >> 16));
      ks += bf2f((u16)(v.y & 0xffff)) + bf2f((u16)(v.y >> 16));
      ks += bf2f((u16)(v.z & 0xffff)) + bf2f((u16)(v.z >> 16));
      ks += bf2f((u16)(v.w & 0xffff)) + bf2f((u16)(v.w >> 16));
    }
#pragma unroll
    for (int kk = 0; kk < 2; ++kk) {
      const int ko = kk * 32 + (lane >> 4) * 8;
      bf16x8 a[2], bb[4];
#pragma unroll
      for (int m = 0; m < 2; ++m)
        a[m] = *(const bf16x8*)&As[(size_t)(wave * 32 + m * 16 + (lane & 15)) * 64 + ko];
#pragma unroll
      for (int n = 0; n < 4; ++n)
        bb[n] = *(const bf16x8*)&Bs[(size_t)(n * 16 + (lane & 15)) * 64 + ko];
#pragma unroll
      for (int m = 0; m < 2; ++m)
#pragma unroll
        for (int n = 0; n < 4; ++n)
          acc[m][n] = __builtin_amdgcn_mfma_f32_16x16x32_bf16(a[m], bb[n], acc[m][n], 0, 0, 0);
    }
    __syncthreads();
  }

  float* pb = partial + (size_t)blockIdx.x * (128 * 65);
#pragma unroll
  for (int m = 0; m < 2; ++m)
#pragma unroll
    for (int n = 0; n < 4; ++n) {
      int d = n * 16 + (lane & 15);
#pragma unroll
      for (int r = 0; r < 4; ++r) {
        int f = wave * 32 + m * 16 + (lane >> 4) * 4 + r;
        pb[f * 65 + d] = acc[m][n][r];
      }
    }
  ksmem[tid] = ks;
  __syncthreads();
  if (tid < 128) pb[tid * 65 + 64] = ksmem[2 * tid] + ksmem[2 * tid + 1];
}

// reduce partials -> KVT [bh][80 rows][128 f] bf16 (row 64 = Ksum, 65..79 = 0)
__global__ __launch_bounds__(256) void kv_reduce_kernel(
    const float* __restrict__ partial, u16* __restrict__ KVT) {
  const int bh = blockIdx.x, tid = threadIdx.x;
  for (int e = tid; e < 8320; e += 256) {
    float s = 0.f;
#pragma unroll
    for (int c = 0; c < 16; ++c) s += partial[(size_t)(bh * 16 + c) * 8320 + e];
    int f = e / 65, col = e % 65;
    KVT[((size_t)bh * 80 + col) * 128 + f] = f2bf(s);
  }
  for (int i = tid; i < 15 * 128; i += 256)
    KVT[((size_t)bh * 80 + 65) * 128 + i] = 0;
}

// ---------------- QKV = Qp @ KV, Z via 5th N-frag, divide -> A bf16 ----------------
__global__ __launch_bounds__(256) void qkv_div_kernel(
    const u16* __restrict__ Qp, const u16* __restrict__ KVT, u16* __restrict__ A) {
  __shared__ u16 smem2[26624];
  u16* Qs = smem2;          // [128 s][128 f]
  u16* Ks = smem2 + 16384;  // [80 rows][128 f]
  const int tid = threadIdx.x, lane = tid & 63, wave = tid >> 6;
  const int bh = blockIdx.x >> 6, st = blockIdx.x & 63;

  stage_r256<128>((const uint8_t*)(Qp + ((size_t)bh * 8192 + st * 128) * 128), 256,
                  Qs, wave, lane);
  stage_r256<80>((const uint8_t*)(KVT + (size_t)bh * 80 * 128), 256, Ks, wave, lane);
  __syncthreads();

  f32x4 acc[2][5];
#pragma unroll
  for (int m = 0; m < 2; ++m)
#pragma unroll
    for (int n = 0; n < 5; ++n) acc[m][n] = (f32x4){0.f, 0.f, 0.f, 0.f};

#pragma unroll
  for (int kk = 0; kk < 4; ++kk) {
    const int ko = kk * 32 + (lane >> 4) * 8;
    bf16x8 a[2], bb[5];
#pragma unroll
    for (int m = 0; m < 2; ++m)
      a[m] = *(const bf16x8*)&Qs[(size_t)(wave * 32 + m * 16 + (lane & 15)) * 128 + ko];
#pragma unroll
    for (int n = 0; n < 5; ++n)
      bb[n] = *(const bf16x8*)&Ks[(size_t)(n * 16 + (lane & 15)) * 128 + ko];
#pragma unroll
    for (int m = 0; m < 2; ++m)
#pragma unroll
      for (int n = 0; n < 5; ++n)
        acc[m][n] = __builtin_amdgcn_mfma_f32_16x16x32_bf16(a[m], bb[n], acc[m][n], 0, 0, 0);
  }

  const int b_ = bh >> 4, h = bh & 15;
#pragma unroll
  for (int m = 0; m < 2; ++m) {
#pragma unroll
    for (int r = 0; r < 4; ++r) {
      float z = fmaxf(__shfl(acc[m][4][r], lane & 48), 1e-6f);
      int srow = st * 128 + wave * 32 + m * 16 + (lane >> 4) * 4 + r;
      size_t rowb = ((size_t)b_ * 8192 + srow) * 1024 + h * 64;
#pragma unroll
      for (int n = 0; n < 4; ++n)
        A[rowb + n * 16 + (lane & 15)] = f2bf(acc[m][n][r] / z);
    }
  }
}

// ---------------- out = A @ Wo (fp32 out) ----------------
__global__ __launch_bounds__(256, 3) void gemm_out_kernel(
    const u16* __restrict__ A, const u16* __restrict__ WoT, float* __restrict__ out) {
  __shared__ u16 smem[16384];
  u16* As = smem;
  u16* Bs = smem + 8192;
  const int tid = threadIdx.x, lane = tid & 63, wave = tid >> 6;
  const int wr = wave >> 1, wc = wave & 1;
  // bijective XCD swizzle: 2048 = 8 * 256 (tn fastest -> A panel reuse)
  const int nb = (blockIdx.x & 7) * 256 + (blockIdx.x >> 3);
  const int tn = nb & 7, tm = nb >> 3;

  f32x4 acc[4][4];
#pragma unroll
  for (int m = 0; m < 4; ++m)
#pragma unroll
    for (int n = 0; n < 4; ++n) acc[m][n] = (f32x4){0.f, 0.f, 0.f, 0.f};

  const uint8_t* aB = (const uint8_t*)(A + (size_t)tm * 128 * 1024);
  const uint8_t* bB = (const uint8_t*)(WoT + (size_t)tn * 128 * 1024);
  for (int kt = 0; kt < 16; ++kt) {
    stage128_sw(aB + kt * 128, 2048, As, wave, lane);
    stage128_sw(bB + kt * 128, 2048, Bs, wave, lane);
    __syncthreads();
    mma128_sw(As, Bs, acc, wr, wc, lane);
    __syncthreads();
  }

  const int rowbase = tm * 128 + wr * 64;
  const int colbase = tn * 128 + wc * 64;
#pragma unroll
  for (int m = 0; m < 4; ++m)
#pragma unroll
    for (int n = 0; n < 4; ++n) {
      int col = colbase + n * 16 + (lane & 15);
      int row = rowbase + m * 16 + (lane >> 4) * 4;
#pragma unroll
      for (int r = 0; r < 4; ++r)
        out[(size_t)(row + r) * 1024 + col] = acc[m][n][r];
    }
}

// ---------------- host ----------------

extern "C" void kernel_launch(void* const* d_in, const int* in_sizes, int n_in,
                              void* d_out, int out_size, void* d_ws, size_t ws_size,
                              hipStream_t stream) {
  const float* x  = (const float*)d_in[0];
  const float* Wq = (const float*)d_in[1];
  const float* Wk = (const float*)d_in[2];
  const float* Wv = (const float*)d_in[3];
  const float* Wo = (const float*)d_in[4];
  const float* rf = (const float*)d_in[5];
  float* out = (float*)d_out;

  if (ws_size < (size_t)411058176) return;   // fail cleanly, don't fault

  u16* ws = (u16*)d_ws;
  u16* xb    = ws;
  u16* Qp    = ws + 33554432UL;
  u16* KpT   = ws + 100663296UL;
  u16* VhT   = ws + 167772160UL;
  u16* wqkvT = ws + 201326592UL;
  u16* woT   = ws + 204472320UL;
  u16* rfT   = ws + 205520896UL;
  float* partial = (float*)xb;          // [1024][128][65] f32 (34 MB), alias xb
  u16* KVT   = wqkvT;                   // [64][80][128] bf16, alias wqkvT (dead)
  u16* Abuf  = xb;                      // [32768][1024] bf16, alias xb

  cast_x_kernel<<<4096, 256, 0, stream>>>(x, xb, 8388608L);
  transpose_cast_kernel<<<1024, 256, 0, stream>>>(Wq, wqkvT,            1024, 1024);
  transpose_cast_kernel<<<1024, 256, 0, stream>>>(Wk, wqkvT + 1048576,  1024, 1024);
  transpose_cast_kernel<<<1024, 256, 0, stream>>>(Wv, wqkvT + 2097152,  1024, 1024);
  transpose_cast_kernel<<<1024, 256, 0, stream>>>(Wo, woT,              1024, 1024);
  transpose_cast_kernel<<<8,    256, 0, stream>>>(rf, rfT,              64,   128);

  gemm_qkv_phi_kernel<<<6144, 256, 0, stream>>>(xb, wqkvT, rfT, Qp, KpT, VhT);
  kv_partial_kernel<<<1024, 256, 0, stream>>>(KpT, VhT, partial);
  kv_reduce_kernel<<<64, 256, 0, stream>>>(partial, KVT);
  qkv_div_kernel<<<4096, 256, 0, stream>>>(Qp, KVT, Abuf);
  gemm_out_kernel<<<2048, 256, 0, stream>>>(Abuf, woT, out);
}

// Round 12
// 525.224 us; speedup vs baseline: 1.2059x; 1.0321x over previous
//
#include <hip/hip_runtime.h>
#include <stdint.h>

// LinearSelfAttention: out = ((phi(xWq) @ (phi(xWk)^T V)) / Z) @ Wo
// B=4 S=8192 H=16 Dh=64 F=128 Dm=1024. All GEMMs bf16-MFMA/fp32-acc.
// R12: R11 with the nontemporal-store compile fix (ext_vector_type operands;
//      __builtin_nontemporal_store rejects HIP_vector_type uint4/uint2).

#define DEVINL __device__ __forceinline__

typedef float f32x4 __attribute__((ext_vector_type(4)));
typedef __bf16 bf16x8 __attribute__((ext_vector_type(8)));
typedef uint32_t u32x4 __attribute__((ext_vector_type(4)));
typedef uint32_t u32x2 __attribute__((ext_vector_type(2)));
typedef unsigned short u16;

#define TSTR 136   // epilogue tile row stride (u16): 272B, 16B-aligned
#define RSTR 72    // rf row stride (u16): 144B, 16B-aligned

DEVINL u16 f2bf(float f) {
  union { float f; uint32_t u; } v; v.f = f;
  uint32_t u = v.u;
  u += 0x7fffu + ((u >> 16) & 1u);   // round-to-nearest-even
  return (u16)(u >> 16);
}
DEVINL float bf2f(u16 h) {
  union { uint32_t u; float f; } v; v.u = ((uint32_t)h) << 16;
  return v.f;
}
DEVINL void nt_store16(u16* p, const u16* s) {
  __builtin_nontemporal_store(*(const u32x4*)s, (u32x4*)p);
}
DEVINL void nt_store8(u16* p, u32x2 v) {
  __builtin_nontemporal_store(v, (u32x2*)p);
}

#define GLOAD16(gp, lp) __builtin_amdgcn_global_load_lds( \
    (const __attribute__((address_space(1))) unsigned int*)(gp), \
    (__attribute__((address_space(3))) unsigned int*)(lp), 16, 0, 0)

// ---- linear staging (kv_partial / qkv_div) ----
template <int ROWS>
DEVINL void stage_r128(const uint8_t* g, size_t stride, u16* lds, int wave, int lane) {
#pragma unroll
  for (int j = 0; j < ROWS / 32; ++j) {
    int row = wave * (ROWS / 4) + j * 8 + (lane >> 3);
    GLOAD16(g + (size_t)row * stride + (size_t)(lane & 7) * 16,
            (uint8_t*)lds + (size_t)(wave * (ROWS / 4) + j * 8) * 128);
  }
}
template <int ROWS>
DEVINL void stage_r256(const uint8_t* g, size_t stride, u16* lds, int wave, int lane) {
#pragma unroll
  for (int j = 0; j < ROWS / 16; ++j) {
    int row = wave * (ROWS / 4) + j * 4 + (lane >> 4);
    GLOAD16(g + (size_t)row * stride + (size_t)(lane & 15) * 16,
            (uint8_t*)lds + (size_t)(wave * (ROWS / 4) + j * 4) * 256);
  }
}

// ---- swizzled staging: LDS[row][c] holds global[row][c ^ (row&7)] ----
DEVINL void stage128_sw(const uint8_t* g, size_t stride, u16* lds, int wave, int lane) {
  const int c = (lane & 7) ^ (lane >> 3);   // row&7 == lane>>3
#pragma unroll
  for (int j = 0; j < 4; ++j) {
    int row = wave * 32 + j * 8 + (lane >> 3);
    GLOAD16(g + (size_t)row * stride + (size_t)c * 16,
            (uint8_t*)lds + (size_t)(wave * 32 + j * 8) * 128);
  }
}

// 128x128 tile, BK=64, 4 waves 2x2, 4x4 frags; SWIZZLED LDS reads.
DEVINL void mma128_sw(const u16* As, const u16* Bs, f32x4 acc[4][4],
                      int wr, int wc, int lane) {
#pragma unroll
  for (int kk = 0; kk < 2; ++kk) {
    const int cw = kk * 4 + (lane >> 4);     // 16B-chunk index 0..7
    const int sw = (cw ^ (lane & 7)) * 8;    // row&7 == lane&7 for frag rows
    bf16x8 a[4], b[4];
#pragma unroll
    for (int m = 0; m < 4; ++m)
      a[m] = *(const bf16x8*)&As[(size_t)(wr * 64 + m * 16 + (lane & 15)) * 64 + sw];
#pragma unroll
    for (int n = 0; n < 4; ++n)
      b[n] = *(const bf16x8*)&Bs[(size_t)(wc * 64 + n * 16 + (lane & 15)) * 64 + sw];
#pragma unroll
    for (int m = 0; m < 4; ++m)
#pragma unroll
      for (int n = 0; n < 4; ++n)
        acc[m][n] = __builtin_amdgcn_mfma_f32_16x16x32_bf16(a[m], b[n], acc[m][n], 0, 0, 0);
  }
}

// ---------------- prep kernels ----------------

__global__ __launch_bounds__(256) void cast_x_kernel(
    const float* __restrict__ src, u16* __restrict__ dst, long n4) {
  long i = (long)blockIdx.x * 256 + threadIdx.x;
  const long stride = (long)gridDim.x * 256;
  const float4* s4 = (const float4*)src;
  u32x2* d4 = (u32x2*)dst;
  for (; i < n4; i += stride) {
    float4 v = s4[i];
    u32x2 o;
    o.x = (uint32_t)f2bf(v.x) | ((uint32_t)f2bf(v.y) << 16);
    o.y = (uint32_t)f2bf(v.z) | ((uint32_t)f2bf(v.w) << 16);
    __builtin_nontemporal_store(o, &d4[i]);
  }
}

// 4 weights fp32 [1024][1024] -> bf16 [1024][1024]^T, one launch (4096 blocks)
__global__ __launch_bounds__(256) void transpose_cast4_kernel(
    const float* __restrict__ w0, const float* __restrict__ w1,
    const float* __restrict__ w2, const float* __restrict__ w3,
    u16* __restrict__ d012, u16* __restrict__ d3) {
  __shared__ float tile[32 * 33];
  const int w = blockIdx.x >> 10, bi = blockIdx.x & 1023;
  const float* src = (w == 0) ? w0 : (w == 1) ? w1 : (w == 2) ? w2 : w3;
  u16* dst = (w < 3) ? (d012 + (size_t)w * 1048576) : d3;
  const int tr = bi & 31, tc = bi >> 5;
  const int tid = threadIdx.x;
  {
    int r = tid >> 3, c4 = (tid & 7) * 4;
    float4 v = *(const float4*)&src[(size_t)(tr * 32 + r) * 1024 + tc * 32 + c4];
    tile[r * 33 + c4 + 0] = v.x;
    tile[r * 33 + c4 + 1] = v.y;
    tile[r * 33 + c4 + 2] = v.z;
    tile[r * 33 + c4 + 3] = v.w;
  }
  __syncthreads();
  {
    int c = tid >> 3, r4 = (tid & 7) * 4;
    u32x2 o;
    o.x = (uint32_t)f2bf(tile[(r4 + 0) * 33 + c]) |
          ((uint32_t)f2bf(tile[(r4 + 1) * 33 + c]) << 16);
    o.y = (uint32_t)f2bf(tile[(r4 + 2) * 33 + c]) |
          ((uint32_t)f2bf(tile[(r4 + 3) * 33 + c]) << 16);
    nt_store8(&dst[(size_t)(tc * 32 + c) * 1024 + tr * 32 + r4], o);
  }
}

// rf fp32 [64][128] -> rfT bf16 [128][64]
__global__ __launch_bounds__(256) void transpose_cast_rf_kernel(
    const float* __restrict__ src, u16* __restrict__ dst) {
  __shared__ float tile[32 * 33];
  const int tr = blockIdx.x & 1, tc = blockIdx.x >> 1;   // 8 blocks: 2 x 4
  const int tid = threadIdx.x;
  {
    int r = tid >> 3, c4 = (tid & 7) * 4;
    float4 v = *(const float4*)&src[(size_t)(tr * 32 + r) * 128 + tc * 32 + c4];
    tile[r * 33 + c4 + 0] = v.x;
    tile[r * 33 + c4 + 1] = v.y;
    tile[r * 33 + c4 + 2] = v.z;
    tile[r * 33 + c4 + 3] = v.w;
  }
  __syncthreads();
  {
    int c = tid >> 3, r4 = (tid & 7) * 4;
    uint2 o;
    o.x = (uint32_t)f2bf(tile[(r4 + 0) * 33 + c]) |
          ((uint32_t)f2bf(tile[(r4 + 1) * 33 + c]) << 16);
    o.y = (uint32_t)f2bf(tile[(r4 + 2) * 33 + c]) |
          ((uint32_t)f2bf(tile[(r4 + 3) * 33 + c]) << 16);
    *(uint2*)&dst[(size_t)(tc * 32 + c) * 64 + tr * 32 + r4] = o;
  }
}

// ---------------- QKV GEMM (N = 3 x 1024) + fused phi ----------------
__global__ __launch_bounds__(256, 3) void gemm_qkv_phi_kernel(
    const u16* __restrict__ xb, const u16* __restrict__ wT,
    const u16* __restrict__ rfT,
    u16* __restrict__ Qp, u16* __restrict__ KpT, u16* __restrict__ VhT) {
  __shared__ u16 smem[26624];               // 52 KiB
  u16* As = smem;                           // [128][64] swizzled
  u16* Bs = smem + 8192;                    // [128][64] swizzled
  u16* Rs = smem + 17408;                   // [128 f][RSTR] (epilogue only)
  const int tid = threadIdx.x, lane = tid & 63, wave = tid >> 6;
  const int wr = wave >> 1, wc = wave & 1;
  // XCD-bijective + L2 super-tile: per XCD, groups of 8tm x 8tn (4MB = L2)
  const int xcd = blockIdx.x & 7;
  const int i = blockIdx.x >> 3;            // [0,768)
  const int g = i >> 6, j = i & 63;         // g in [0,12), j in [0,64)
  const int tn = (g % 3) * 8 + (j >> 3);
  const int tm = xcd * 32 + (g / 3) * 8 + (j & 7);
  const int tensor = tn >> 3;

  f32x4 acc[4][4];
#pragma unroll
  for (int m = 0; m < 4; ++m)
#pragma unroll
    for (int n = 0; n < 4; ++n) acc[m][n] = (f32x4){0.f, 0.f, 0.f, 0.f};

  const uint8_t* aB = (const uint8_t*)(xb + (size_t)tm * 128 * 1024);
  const uint8_t* bB = (const uint8_t*)(wT + (size_t)tn * 128 * 1024);
  for (int kt = 0; kt < 16; ++kt) {
    stage128_sw(aB + kt * 128, 2048, As, wave, lane);
    stage128_sw(bB + kt * 128, 2048, Bs, wave, lane);
    __syncthreads();
    mma128_sw(As, Bs, acc, wr, wc, lane);
    __syncthreads();
  }

  const int b = (tm * 128) >> 13;
  const int sblk = (tm * 128) & 8191;

  if (tensor == 2) {
    // V: transpose 128x128 tile via padded TILE, coalesced nt 16B rows out.
#pragma unroll
    for (int m = 0; m < 4; ++m) {
      int sl = wr * 64 + m * 16 + (lane >> 4) * 4;
#pragma unroll
      for (int n = 0; n < 4; ++n) {
        int cl = wc * 64 + n * 16 + (lane & 15);
#pragma unroll
        for (int r = 0; r < 4; ++r) smem[cl * TSTR + sl + r] = f2bf(acc[m][n][r]);
      }
    }
    __syncthreads();
#pragma unroll
    for (int it = 0; it < 8; ++it) {
      int cl = it * 16 + (tid >> 4);
      int c = (tn & 7) * 128 + cl;
      int h = c >> 6, d = c & 63;
      size_t off = ((size_t)((b * 16 + h) * 64 + d)) * 8192 + sblk + (tid & 15) * 8;
      nt_store16(&VhT[off], &smem[cl * TSTR + (tid & 15) * 8]);
    }
    return;
  }

  // ---- Q/K: fused phi ----
#pragma unroll
  for (int m = 0; m < 4; ++m) {
    int sl = wr * 64 + m * 16 + (lane >> 4) * 4;
#pragma unroll
    for (int n = 0; n < 4; ++n) {
      int cl = wc * 64 + n * 16 + (lane & 15);
#pragma unroll
      for (int r = 0; r < 4; ++r) smem[(sl + r) * TSTR + cl] = f2bf(acc[m][n][r]);
    }
  }
#pragma unroll
  for (int p4 = 0; p4 < 4; ++p4) {
    int idx = p4 * 256 + tid;
    int f = idx >> 3, c = idx & 7;
    *(uint4*)&Rs[f * RSTR + c * 8] = *(const uint4*)&rfT[f * 64 + c * 8];
  }
  __syncthreads();

  bf16x8 afr[2][2][2];   // [hh][kk][m]
#pragma unroll
  for (int hh = 0; hh < 2; ++hh)
#pragma unroll
    for (int kk = 0; kk < 2; ++kk) {
      const int ko = kk * 32 + (lane >> 4) * 8;
#pragma unroll
      for (int m = 0; m < 2; ++m)
        afr[hh][kk][m] = *(const bf16x8*)&smem[
            (size_t)(wave * 32 + m * 16 + (lane & 15)) * TSTR + hh * 64 + ko];
    }
  __syncthreads();

  const float SC = 0.088388347648318447f;  // 128^-0.5
#pragma unroll
  for (int hh = 0; hh < 2; ++hh) {
    const int h = (tn & 7) * 2 + hh;
    f32x4 p[2][8];
#pragma unroll
    for (int m = 0; m < 2; ++m)
#pragma unroll
      for (int n = 0; n < 8; ++n) p[m][n] = (f32x4){0.f, 0.f, 0.f, 0.f};
#pragma unroll
    for (int kk = 0; kk < 2; ++kk) {
      const int ko = kk * 32 + (lane >> 4) * 8;
      bf16x8 bb[8];
#pragma unroll
      for (int n = 0; n < 8; ++n)
        bb[n] = *(const bf16x8*)&Rs[(size_t)(n * 16 + (lane & 15)) * RSTR + ko];
#pragma unroll
      for (int m = 0; m < 2; ++m)
#pragma unroll
        for (int n = 0; n < 8; ++n)
          p[m][n] = __builtin_amdgcn_mfma_f32_16x16x32_bf16(afr[hh][kk][m], bb[n], p[m][n], 0, 0, 0);
    }

    if (tensor == 0) {
#pragma unroll
      for (int m = 0; m < 2; ++m)
#pragma unroll
        for (int n = 0; n < 8; ++n) {
          int f = n * 16 + (lane & 15);
          int sl = wave * 32 + m * 16 + (lane >> 4) * 4;
#pragma unroll
          for (int r = 0; r < 4; ++r) {
            float v = ((n < 4) ? __cosf(p[m][n][r]) : __sinf(p[m][n][r])) * SC;
            smem[(sl + r) * TSTR + f] = f2bf(v);
          }
        }
      __syncthreads();
      const size_t base_bh = (size_t)(b * 16 + h) * 8192;
#pragma unroll
      for (int it = 0; it < 8; ++it) {
        int s = it * 16 + (tid >> 4);
        nt_store16(&Qp[(base_bh + sblk + s) * 128 + (tid & 15) * 8],
                   &smem[s * TSTR + (tid & 15) * 8]);
      }
    } else {
#pragma unroll
      for (int m = 0; m < 2; ++m)
#pragma unroll
        for (int n = 0; n < 8; ++n) {
          int f = n * 16 + (lane & 15);
          int sl = wave * 32 + m * 16 + (lane >> 4) * 4;
#pragma unroll
          for (int r = 0; r < 4; ++r) {
            float v = ((n < 4) ? __cosf(p[m][n][r]) : __sinf(p[m][n][r])) * SC;
            smem[f * TSTR + sl + r] = f2bf(v);
          }
        }
      __syncthreads();
#pragma unroll
      for (int it = 0; it < 8; ++it) {
        int f = it * 16 + (tid >> 4);
        nt_store16(&KpT[((size_t)(b * 16 + h) * 128 + f) * 8192 + sblk + (tid & 15) * 8],
                   &smem[f * TSTR + (tid & 15) * 8]);
      }
    }
    if (hh == 0) __syncthreads();   // stores done before overwriting TILE
  }
}

// ---------------- KV = Kp^T V + Ksum, 16 s-chunks ----------------
// Ksum computed from the MFMA A-fragments (each (f,s) element touched exactly
// once across lanes/m/kk) + shfl_xor reduce -> no conflicted LDS re-reads.
__global__ __launch_bounds__(256) void kv_partial_kernel(
    const u16* __restrict__ KpT, const u16* __restrict__ VhT,
    float* __restrict__ partial) {
  __shared__ u16 smem2[12288];
  u16* As = smem2;        // [128 f][64 s]
  u16* Bs = smem2 + 8192; // [64 d][64 s]
  const int tid = threadIdx.x, lane = tid & 63, wave = tid >> 6;
  const int bh = blockIdx.x >> 4, ch = blockIdx.x & 15;
  const uint8_t* aB = (const uint8_t*)(KpT + (size_t)bh * 128 * 8192 + ch * 512);
  const uint8_t* bB = (const uint8_t*)(VhT + (size_t)bh * 64 * 8192 + ch * 512);

  f32x4 acc[2][4];
#pragma unroll
  for (int m = 0; m < 2; ++m)
#pragma unroll
    for (int n = 0; n < 4; ++n) acc[m][n] = (f32x4){0.f, 0.f, 0.f, 0.f};
  float ks0 = 0.f, ks1 = 0.f;

  for (int t = 0; t < 8; ++t) {
    stage_r128<128>(aB + t * 128, 16384, As, wave, lane);
    stage_r128<64>(bB + t * 128, 16384, Bs, wave, lane);
    __syncthreads();
#pragma unroll
    for (int kk = 0; kk < 2; ++kk) {
      const int ko = kk * 32 + (lane >> 4) * 8;
      bf16x8 a[2], bb[4];
#pragma unroll
      for (int m = 0; m < 2; ++m)
        a[m] = *(const bf16x8*)&As[(size_t)(wave * 32 + m * 16 + (lane & 15)) * 64 + ko];
#pragma unroll
      for (int e = 0; e < 8; ++e) { ks0 += (float)a[0][e]; ks1 += (float)a[1][e]; }
#pragma unroll
      for (int n = 0; n < 4; ++n)
        bb[n] = *(const bf16x8*)&Bs[(size_t)(n * 16 + (lane & 15)) * 64 + ko];
#pragma unroll
      for (int m = 0; m < 2; ++m)
#pragma unroll
        for (int n = 0; n < 4; ++n)
          acc[m][n] = __builtin_amdgcn_mfma_f32_16x16x32_bf16(a[m], bb[n], acc[m][n], 0, 0, 0);
    }
    __syncthreads();
  }

  float* pb = partial + (size_t)blockIdx.x * (128 * 65);
#pragma unroll
  for (int m = 0; m < 2; ++m)
#pragma unroll
    for (int n = 0; n < 4; ++n) {
      int d = n * 16 + (lane & 15);
#pragma unroll
      for (int r = 0; r < 4; ++r) {
        int f = wave * 32 + m * 16 + (lane >> 4) * 4 + r;
        pb[f * 65 + d] = acc[m][n][r];
      }
    }
  // reduce ks across the 4 lane>>4 groups (same lane&15, same wave)
  ks0 += __shfl_xor(ks0, 16); ks0 += __shfl_xor(ks0, 32);
  ks1 += __shfl_xor(ks1, 16); ks1 += __shfl_xor(ks1, 32);
  if ((lane >> 4) == 0) {
    pb[(wave * 32 + (lane & 15)) * 65 + 64] = ks0;
    pb[(wave * 32 + 16 + (lane & 15)) * 65 + 64] = ks1;
  }
}

// reduce partials -> KVT [bh][80 rows][128 f] bf16 (row 64 = Ksum, 65..79 = 0)
__global__ __launch_bounds__(256) void kv_reduce_kernel(
    const float* __restrict__ partial, u16* __restrict__ KVT) {
  const int bh = blockIdx.x >> 3, eo = (blockIdx.x & 7) * 1040;
  const int tid = threadIdx.x;
  for (int e = eo + tid; e < eo + 1040; e += 256) {
    float s = 0.f;
#pragma unroll
    for (int c = 0; c < 16; ++c) s += partial[(size_t)(bh * 16 + c) * 8320 + e];
    int f = e / 65, col = e % 65;
    KVT[((size_t)bh * 80 + col) * 128 + f] = f2bf(s);
  }
  if ((blockIdx.x & 7) == 7)
    for (int i = tid; i < 15 * 128; i += 256)
      KVT[((size_t)bh * 80 + 65) * 128 + i] = 0;
}

// ---------------- QKV = Qp @ KV, Z via 5th N-frag, divide -> A bf16 ----------------
__global__ __launch_bounds__(256) void qkv_div_kernel(
    const u16* __restrict__ Qp, const u16* __restrict__ KVT, u16* __restrict__ A) {
  __shared__ u16 smem2[26624];
  u16* Qs = smem2;          // [128 s][128 f]
  u16* Ks = smem2 + 16384;  // [80 rows][128 f]
  const int tid = threadIdx.x, lane = tid & 63, wave = tid >> 6;
  const int bh = blockIdx.x >> 6, st = blockIdx.x & 63;

  stage_r256<128>((const uint8_t*)(Qp + ((size_t)bh * 8192 + st * 128) * 128), 256,
                  Qs, wave, lane);
  stage_r256<80>((const uint8_t*)(KVT + (size_t)bh * 80 * 128), 256, Ks, wave, lane);
  __syncthreads();

  f32x4 acc[2][5];
#pragma unroll
  for (int m = 0; m < 2; ++m)
#pragma unroll
    for (int n = 0; n < 5; ++n) acc[m][n] = (f32x4){0.f, 0.f, 0.f, 0.f};

#pragma unroll
  for (int kk = 0; kk < 4; ++kk) {
    const int ko = kk * 32 + (lane >> 4) * 8;
    bf16x8 a[2], bb[5];
#pragma unroll
    for (int m = 0; m < 2; ++m)
      a[m] = *(const bf16x8*)&Qs[(size_t)(wave * 32 + m * 16 + (lane & 15)) * 128 + ko];
#pragma unroll
    for (int n = 0; n < 5; ++n)
      bb[n] = *(const bf16x8*)&Ks[(size_t)(n * 16 + (lane & 15)) * 128 + ko];
#pragma unroll
    for (int m = 0; m < 2; ++m)
#pragma unroll
      for (int n = 0; n < 5; ++n)
        acc[m][n] = __builtin_amdgcn_mfma_f32_16x16x32_bf16(a[m], bb[n], acc[m][n], 0, 0, 0);
  }

  const int b_ = bh >> 4, h = bh & 15;
#pragma unroll
  for (int m = 0; m < 2; ++m) {
#pragma unroll
    for (int r = 0; r < 4; ++r) {
      float z = fmaxf(__shfl(acc[m][4][r], lane & 48), 1e-6f);
      int srow = st * 128 + wave * 32 + m * 16 + (lane >> 4) * 4 + r;
      size_t rowb = ((size_t)b_ * 8192 + srow) * 1024 + h * 64;
#pragma unroll
      for (int n = 0; n < 4; ++n)
        A[rowb + n * 16 + (lane & 15)] = f2bf(acc[m][n][r] / z);
    }
  }
}

// ---------------- out = A @ Wo (fp32 out) ----------------
__global__ __launch_bounds__(256, 3) void gemm_out_kernel(
    const u16* __restrict__ A, const u16* __restrict__ WoT, float* __restrict__ out) {
  __shared__ u16 smem[16384];
  u16* As = smem;
  u16* Bs = smem + 8192;
  const int tid = threadIdx.x, lane = tid & 63, wave = tid >> 6;
  const int wr = wave >> 1, wc = wave & 1;
  const int nb = (blockIdx.x & 7) * 256 + (blockIdx.x >> 3);
  const int tn = nb & 7, tm = nb >> 3;

  f32x4 acc[4][4];
#pragma unroll
  for (int m = 0; m < 4; ++m)
#pragma unroll
    for (int n = 0; n < 4; ++n) acc[m][n] = (f32x4){0.f, 0.f, 0.f, 0.f};

  const uint8_t* aB = (const uint8_t*)(A + (size_t)tm * 128 * 1024);
  const uint8_t* bB = (const uint8_t*)(WoT + (size_t)tn * 128 * 1024);
  for (int kt = 0; kt < 16; ++kt) {
    stage128_sw(aB + kt * 128, 2048, As, wave, lane);
    stage128_sw(bB + kt * 128, 2048, Bs, wave, lane);
    __syncthreads();
    mma128_sw(As, Bs, acc, wr, wc, lane);
    __syncthreads();
  }

  const int rowbase = tm * 128 + wr * 64;
  const int colbase = tn * 128 + wc * 64;
#pragma unroll
  for (int m = 0; m < 4; ++m)
#pragma unroll
    for (int n = 0; n < 4; ++n) {
      int col = colbase + n * 16 + (lane & 15);
      int row = rowbase + m * 16 + (lane >> 4) * 4;
#pragma unroll
      for (int r = 0; r < 4; ++r)
        __builtin_nontemporal_store(acc[m][n][r], &out[(size_t)(row + r) * 1024 + col]);
    }
}

// ---------------- host ----------------

extern "C" void kernel_launch(void* const* d_in, const int* in_sizes, int n_in,
                              void* d_out, int out_size, void* d_ws, size_t ws_size,
                              hipStream_t stream) {
  const float* x  = (const float*)d_in[0];
  const float* Wq = (const float*)d_in[1];
  const float* Wk = (const float*)d_in[2];
  const float* Wv = (const float*)d_in[3];
  const float* Wo = (const float*)d_in[4];
  const float* rf = (const float*)d_in[5];
  float* out = (float*)d_out;

  if (ws_size < (size_t)411058176) return;   // fail cleanly, don't fault

  u16* ws = (u16*)d_ws;
  u16* xb    = ws;
  u16* Qp    = ws + 33554432UL;
  u16* KpT   = ws + 100663296UL;
  u16* VhT   = ws + 167772160UL;
  u16* wqkvT = ws + 201326592UL;
  u16* woT   = ws + 204472320UL;
  u16* rfT   = ws + 205520896UL;
  float* partial = (float*)xb;          // [1024][128][65] f32 (34 MB), alias xb
  u16* KVT   = wqkvT;                   // [64][80][128] bf16, alias wqkvT (dead)
  u16* Abuf  = xb;                      // [32768][1024] bf16, alias xb

  cast_x_kernel<<<4096, 256, 0, stream>>>(x, xb, 8388608L);
  transpose_cast4_kernel<<<4096, 256, 0, stream>>>(Wq, Wk, Wv, Wo, wqkvT, woT);
  transpose_cast_rf_kernel<<<8, 256, 0, stream>>>(rf, rfT);

  gemm_qkv_phi_kernel<<<6144, 256, 0, stream>>>(xb, wqkvT, rfT, Qp, KpT, VhT);
  kv_partial_kernel<<<1024, 256, 0, stream>>>(KpT, VhT, partial);
  kv_reduce_kernel<<<512, 256, 0, stream>>>(partial, KVT);
  qkv_div_kernel<<<4096, 256, 0, stream>>>(Qp, KVT, Abuf);
  gemm_out_kernel<<<2048, 256, 0, stream>>>(Abuf, woT, out);
}

// Round 13
// 515.422 us; speedup vs baseline: 1.2288x; 1.0190x over previous
//
#include <hip/hip_runtime.h>
#include <stdint.h>

// LinearSelfAttention: out = ((phi(xWq) @ (phi(xWk)^T V)) / Z) @ Wo
// B=4 S=8192 H=16 Dh=64 F=128 Dm=1024. All GEMMs bf16-MFMA/fp32-acc.
// R13: R12 minus nontemporal stores (measured -7% on gemm_qkv_phi epilogue:
//      R10 285-289us vs R12 304-309us, disjoint ranges). Plain stores
//      everywhere; keep ksum-from-frags, 512-blk kv_reduce, merged
//      transposes, L2 super-tile, swizzled staging.

#define DEVINL __device__ __forceinline__

typedef float f32x4 __attribute__((ext_vector_type(4)));
typedef __bf16 bf16x8 __attribute__((ext_vector_type(8)));
typedef unsigned short u16;

#define TSTR 136   // epilogue tile row stride (u16): 272B, 16B-aligned
#define RSTR 72    // rf row stride (u16): 144B, 16B-aligned

DEVINL u16 f2bf(float f) {
  union { float f; uint32_t u; } v; v.f = f;
  uint32_t u = v.u;
  u += 0x7fffu + ((u >> 16) & 1u);   // round-to-nearest-even
  return (u16)(u >> 16);
}
DEVINL float bf2f(u16 h) {
  union { uint32_t u; float f; } v; v.u = ((uint32_t)h) << 16;
  return v.f;
}

#define GLOAD16(gp, lp) __builtin_amdgcn_global_load_lds( \
    (const __attribute__((address_space(1))) unsigned int*)(gp), \
    (__attribute__((address_space(3))) unsigned int*)(lp), 16, 0, 0)

// ---- linear staging (kv_partial / qkv_div) ----
template <int ROWS>
DEVINL void stage_r128(const uint8_t* g, size_t stride, u16* lds, int wave, int lane) {
#pragma unroll
  for (int j = 0; j < ROWS / 32; ++j) {
    int row = wave * (ROWS / 4) + j * 8 + (lane >> 3);
    GLOAD16(g + (size_t)row * stride + (size_t)(lane & 7) * 16,
            (uint8_t*)lds + (size_t)(wave * (ROWS / 4) + j * 8) * 128);
  }
}
template <int ROWS>
DEVINL void stage_r256(const uint8_t* g, size_t stride, u16* lds, int wave, int lane) {
#pragma unroll
  for (int j = 0; j < ROWS / 16; ++j) {
    int row = wave * (ROWS / 4) + j * 4 + (lane >> 4);
    GLOAD16(g + (size_t)row * stride + (size_t)(lane & 15) * 16,
            (uint8_t*)lds + (size_t)(wave * (ROWS / 4) + j * 4) * 256);
  }
}

// ---- swizzled staging: LDS[row][c] holds global[row][c ^ (row&7)] ----
DEVINL void stage128_sw(const uint8_t* g, size_t stride, u16* lds, int wave, int lane) {
  const int c = (lane & 7) ^ (lane >> 3);   // row&7 == lane>>3
#pragma unroll
  for (int j = 0; j < 4; ++j) {
    int row = wave * 32 + j * 8 + (lane >> 3);
    GLOAD16(g + (size_t)row * stride + (size_t)c * 16,
            (uint8_t*)lds + (size_t)(wave * 32 + j * 8) * 128);
  }
}

// 128x128 tile, BK=64, 4 waves 2x2, 4x4 frags; SWIZZLED LDS reads.
DEVINL void mma128_sw(const u16* As, const u16* Bs, f32x4 acc[4][4],
                      int wr, int wc, int lane) {
#pragma unroll
  for (int kk = 0; kk < 2; ++kk) {
    const int cw = kk * 4 + (lane >> 4);     // 16B-chunk index 0..7
    const int sw = (cw ^ (lane & 7)) * 8;    // row&7 == lane&7 for frag rows
    bf16x8 a[4], b[4];
#pragma unroll
    for (int m = 0; m < 4; ++m)
      a[m] = *(const bf16x8*)&As[(size_t)(wr * 64 + m * 16 + (lane & 15)) * 64 + sw];
#pragma unroll
    for (int n = 0; n < 4; ++n)
      b[n] = *(const bf16x8*)&Bs[(size_t)(wc * 64 + n * 16 + (lane & 15)) * 64 + sw];
#pragma unroll
    for (int m = 0; m < 4; ++m)
#pragma unroll
      for (int n = 0; n < 4; ++n)
        acc[m][n] = __builtin_amdgcn_mfma_f32_16x16x32_bf16(a[m], b[n], acc[m][n], 0, 0, 0);
  }
}

// ---------------- prep kernels ----------------

__global__ __launch_bounds__(256) void cast_x_kernel(
    const float* __restrict__ src, u16* __restrict__ dst, long n4) {
  long i = (long)blockIdx.x * 256 + threadIdx.x;
  const long stride = (long)gridDim.x * 256;
  const float4* s4 = (const float4*)src;
  uint2* d4 = (uint2*)dst;
  for (; i < n4; i += stride) {
    float4 v = s4[i];
    uint2 o;
    o.x = (uint32_t)f2bf(v.x) | ((uint32_t)f2bf(v.y) << 16);
    o.y = (uint32_t)f2bf(v.z) | ((uint32_t)f2bf(v.w) << 16);
    d4[i] = o;
  }
}

// 4 weights fp32 [1024][1024] -> bf16 [1024][1024]^T, one launch (4096 blocks)
__global__ __launch_bounds__(256) void transpose_cast4_kernel(
    const float* __restrict__ w0, const float* __restrict__ w1,
    const float* __restrict__ w2, const float* __restrict__ w3,
    u16* __restrict__ d012, u16* __restrict__ d3) {
  __shared__ float tile[32 * 33];
  const int w = blockIdx.x >> 10, bi = blockIdx.x & 1023;
  const float* src = (w == 0) ? w0 : (w == 1) ? w1 : (w == 2) ? w2 : w3;
  u16* dst = (w < 3) ? (d012 + (size_t)w * 1048576) : d3;
  const int tr = bi & 31, tc = bi >> 5;
  const int tid = threadIdx.x;
  {
    int r = tid >> 3, c4 = (tid & 7) * 4;
    float4 v = *(const float4*)&src[(size_t)(tr * 32 + r) * 1024 + tc * 32 + c4];
    tile[r * 33 + c4 + 0] = v.x;
    tile[r * 33 + c4 + 1] = v.y;
    tile[r * 33 + c4 + 2] = v.z;
    tile[r * 33 + c4 + 3] = v.w;
  }
  __syncthreads();
  {
    int c = tid >> 3, r4 = (tid & 7) * 4;
    uint2 o;
    o.x = (uint32_t)f2bf(tile[(r4 + 0) * 33 + c]) |
          ((uint32_t)f2bf(tile[(r4 + 1) * 33 + c]) << 16);
    o.y = (uint32_t)f2bf(tile[(r4 + 2) * 33 + c]) |
          ((uint32_t)f2bf(tile[(r4 + 3) * 33 + c]) << 16);
    *(uint2*)&dst[(size_t)(tc * 32 + c) * 1024 + tr * 32 + r4] = o;
  }
}

// rf fp32 [64][128] -> rfT bf16 [128][64]
__global__ __launch_bounds__(256) void transpose_cast_rf_kernel(
    const float* __restrict__ src, u16* __restrict__ dst) {
  __shared__ float tile[32 * 33];
  const int tr = blockIdx.x & 1, tc = blockIdx.x >> 1;   // 8 blocks: 2 x 4
  const int tid = threadIdx.x;
  {
    int r = tid >> 3, c4 = (tid & 7) * 4;
    float4 v = *(const float4*)&src[(size_t)(tr * 32 + r) * 128 + tc * 32 + c4];
    tile[r * 33 + c4 + 0] = v.x;
    tile[r * 33 + c4 + 1] = v.y;
    tile[r * 33 + c4 + 2] = v.z;
    tile[r * 33 + c4 + 3] = v.w;
  }
  __syncthreads();
  {
    int c = tid >> 3, r4 = (tid & 7) * 4;
    uint2 o;
    o.x = (uint32_t)f2bf(tile[(r4 + 0) * 33 + c]) |
          ((uint32_t)f2bf(tile[(r4 + 1) * 33 + c]) << 16);
    o.y = (uint32_t)f2bf(tile[(r4 + 2) * 33 + c]) |
          ((uint32_t)f2bf(tile[(r4 + 3) * 33 + c]) << 16);
    *(uint2*)&dst[(size_t)(tc * 32 + c) * 64 + tr * 32 + r4] = o;
  }
}

// ---------------- QKV GEMM (N = 3 x 1024) + fused phi ----------------
__global__ __launch_bounds__(256, 3) void gemm_qkv_phi_kernel(
    const u16* __restrict__ xb, const u16* __restrict__ wT,
    const u16* __restrict__ rfT,
    u16* __restrict__ Qp, u16* __restrict__ KpT, u16* __restrict__ VhT) {
  __shared__ u16 smem[26624];               // 52 KiB
  u16* As = smem;                           // [128][64] swizzled
  u16* Bs = smem + 8192;                    // [128][64] swizzled
  u16* Rs = smem + 17408;                   // [128 f][RSTR] (epilogue only)
  const int tid = threadIdx.x, lane = tid & 63, wave = tid >> 6;
  const int wr = wave >> 1, wc = wave & 1;
  // XCD-bijective + L2 super-tile: per XCD, groups of 8tm x 8tn (4MB = L2)
  const int xcd = blockIdx.x & 7;
  const int i = blockIdx.x >> 3;            // [0,768)
  const int g = i >> 6, j = i & 63;         // g in [0,12), j in [0,64)
  const int tn = (g % 3) * 8 + (j >> 3);
  const int tm = xcd * 32 + (g / 3) * 8 + (j & 7);
  const int tensor = tn >> 3;

  f32x4 acc[4][4];
#pragma unroll
  for (int m = 0; m < 4; ++m)
#pragma unroll
    for (int n = 0; n < 4; ++n) acc[m][n] = (f32x4){0.f, 0.f, 0.f, 0.f};

  const uint8_t* aB = (const uint8_t*)(xb + (size_t)tm * 128 * 1024);
  const uint8_t* bB = (const uint8_t*)(wT + (size_t)tn * 128 * 1024);
  for (int kt = 0; kt < 16; ++kt) {
    stage128_sw(aB + kt * 128, 2048, As, wave, lane);
    stage128_sw(bB + kt * 128, 2048, Bs, wave, lane);
    __syncthreads();
    mma128_sw(As, Bs, acc, wr, wc, lane);
    __syncthreads();
  }

  const int b = (tm * 128) >> 13;
  const int sblk = (tm * 128) & 8191;

  if (tensor == 2) {
    // V: transpose 128x128 tile via padded TILE, coalesced 16B rows out.
#pragma unroll
    for (int m = 0; m < 4; ++m) {
      int sl = wr * 64 + m * 16 + (lane >> 4) * 4;
#pragma unroll
      for (int n = 0; n < 4; ++n) {
        int cl = wc * 64 + n * 16 + (lane & 15);
#pragma unroll
        for (int r = 0; r < 4; ++r) smem[cl * TSTR + sl + r] = f2bf(acc[m][n][r]);
      }
    }
    __syncthreads();
#pragma unroll
    for (int it = 0; it < 8; ++it) {
      int cl = it * 16 + (tid >> 4);
      int c = (tn & 7) * 128 + cl;
      int h = c >> 6, d = c & 63;
      size_t off = ((size_t)((b * 16 + h) * 64 + d)) * 8192 + sblk + (tid & 15) * 8;
      *(uint4*)&VhT[off] = *(const uint4*)&smem[cl * TSTR + (tid & 15) * 8];
    }
    return;
  }

  // ---- Q/K: fused phi ----
#pragma unroll
  for (int m = 0; m < 4; ++m) {
    int sl = wr * 64 + m * 16 + (lane >> 4) * 4;
#pragma unroll
    for (int n = 0; n < 4; ++n) {
      int cl = wc * 64 + n * 16 + (lane & 15);
#pragma unroll
      for (int r = 0; r < 4; ++r) smem[(sl + r) * TSTR + cl] = f2bf(acc[m][n][r]);
    }
  }
#pragma unroll
  for (int p4 = 0; p4 < 4; ++p4) {
    int idx = p4 * 256 + tid;
    int f = idx >> 3, c = idx & 7;
    *(uint4*)&Rs[f * RSTR + c * 8] = *(const uint4*)&rfT[f * 64 + c * 8];
  }
  __syncthreads();

  bf16x8 afr[2][2][2];   // [hh][kk][m]
#pragma unroll
  for (int hh = 0; hh < 2; ++hh)
#pragma unroll
    for (int kk = 0; kk < 2; ++kk) {
      const int ko = kk * 32 + (lane >> 4) * 8;
#pragma unroll
      for (int m = 0; m < 2; ++m)
        afr[hh][kk][m] = *(const bf16x8*)&smem[
            (size_t)(wave * 32 + m * 16 + (lane & 15)) * TSTR + hh * 64 + ko];
    }
  __syncthreads();

  const float SC = 0.088388347648318447f;  // 128^-0.5
#pragma unroll
  for (int hh = 0; hh < 2; ++hh) {
    const int h = (tn & 7) * 2 + hh;
    f32x4 p[2][8];
#pragma unroll
    for (int m = 0; m < 2; ++m)
#pragma unroll
      for (int n = 0; n < 8; ++n) p[m][n] = (f32x4){0.f, 0.f, 0.f, 0.f};
#pragma unroll
    for (int kk = 0; kk < 2; ++kk) {
      const int ko = kk * 32 + (lane >> 4) * 8;
      bf16x8 bb[8];
#pragma unroll
      for (int n = 0; n < 8; ++n)
        bb[n] = *(const bf16x8*)&Rs[(size_t)(n * 16 + (lane & 15)) * RSTR + ko];
#pragma unroll
      for (int m = 0; m < 2; ++m)
#pragma unroll
        for (int n = 0; n < 8; ++n)
          p[m][n] = __builtin_amdgcn_mfma_f32_16x16x32_bf16(afr[hh][kk][m], bb[n], p[m][n], 0, 0, 0);
    }

    if (tensor == 0) {
#pragma unroll
      for (int m = 0; m < 2; ++m)
#pragma unroll
        for (int n = 0; n < 8; ++n) {
          int f = n * 16 + (lane & 15);
          int sl = wave * 32 + m * 16 + (lane >> 4) * 4;
#pragma unroll
          for (int r = 0; r < 4; ++r) {
            float v = ((n < 4) ? __cosf(p[m][n][r]) : __sinf(p[m][n][r])) * SC;
            smem[(sl + r) * TSTR + f] = f2bf(v);
          }
        }
      __syncthreads();
      const size_t base_bh = (size_t)(b * 16 + h) * 8192;
#pragma unroll
      for (int it = 0; it < 8; ++it) {
        int s = it * 16 + (tid >> 4);
        *(uint4*)&Qp[(base_bh + sblk + s) * 128 + (tid & 15) * 8] =
            *(const uint4*)&smem[s * TSTR + (tid & 15) * 8];
      }
    } else {
#pragma unroll
      for (int m = 0; m < 2; ++m)
#pragma unroll
        for (int n = 0; n < 8; ++n) {
          int f = n * 16 + (lane & 15);
          int sl = wave * 32 + m * 16 + (lane >> 4) * 4;
#pragma unroll
          for (int r = 0; r < 4; ++r) {
            float v = ((n < 4) ? __cosf(p[m][n][r]) : __sinf(p[m][n][r])) * SC;
            smem[f * TSTR + sl + r] = f2bf(v);
          }
        }
      __syncthreads();
#pragma unroll
      for (int it = 0; it < 8; ++it) {
        int f = it * 16 + (tid >> 4);
        *(uint4*)&KpT[((size_t)(b * 16 + h) * 128 + f) * 8192 + sblk + (tid & 15) * 8] =
            *(const uint4*)&smem[f * TSTR + (tid & 15) * 8];
      }
    }
    if (hh == 0) __syncthreads();   // stores done before overwriting TILE
  }
}

// ---------------- KV = Kp^T V + Ksum, 16 s-chunks ----------------
// Ksum computed from the MFMA A-fragments (each (f,s) element touched exactly
// once across lanes/m/kk) + shfl_xor reduce -> no conflicted LDS re-reads.
__global__ __launch_bounds__(256) void kv_partial_kernel(
    const u16* __restrict__ KpT, const u16* __restrict__ VhT,
    float* __restrict__ partial) {
  __shared__ u16 smem2[12288];
  u16* As = smem2;        // [128 f][64 s]
  u16* Bs = smem2 + 8192; // [64 d][64 s]
  const int tid = threadIdx.x, lane = tid & 63, wave = tid >> 6;
  const int bh = blockIdx.x >> 4, ch = blockIdx.x & 15;
  const uint8_t* aB = (const uint8_t*)(KpT + (size_t)bh * 128 * 8192 + ch * 512);
  const uint8_t* bB = (const uint8_t*)(VhT + (size_t)bh * 64 * 8192 + ch * 512);

  f32x4 acc[2][4];
#pragma unroll
  for (int m = 0; m < 2; ++m)
#pragma unroll
    for (int n = 0; n < 4; ++n) acc[m][n] = (f32x4){0.f, 0.f, 0.f, 0.f};
  float ks0 = 0.f, ks1 = 0.f;

  for (int t = 0; t < 8; ++t) {
    stage_r128<128>(aB + t * 128, 16384, As, wave, lane);
    stage_r128<64>(bB + t * 128, 16384, Bs, wave, lane);
    __syncthreads();
#pragma unroll
    for (int kk = 0; kk < 2; ++kk) {
      const int ko = kk * 32 + (lane >> 4) * 8;
      bf16x8 a[2], bb[4];
#pragma unroll
      for (int m = 0; m < 2; ++m)
        a[m] = *(const bf16x8*)&As[(size_t)(wave * 32 + m * 16 + (lane & 15)) * 64 + ko];
#pragma unroll
      for (int e = 0; e < 8; ++e) { ks0 += (float)a[0][e]; ks1 += (float)a[1][e]; }
#pragma unroll
      for (int n = 0; n < 4; ++n)
        bb[n] = *(const bf16x8*)&Bs[(size_t)(n * 16 + (lane & 15)) * 64 + ko];
#pragma unroll
      for (int m = 0; m < 2; ++m)
#pragma unroll
        for (int n = 0; n < 4; ++n)
          acc[m][n] = __builtin_amdgcn_mfma_f32_16x16x32_bf16(a[m], bb[n], acc[m][n], 0, 0, 0);
    }
    __syncthreads();
  }

  float* pb = partial + (size_t)blockIdx.x * (128 * 65);
#pragma unroll
  for (int m = 0; m < 2; ++m)
#pragma unroll
    for (int n = 0; n < 4; ++n) {
      int d = n * 16 + (lane & 15);
#pragma unroll
      for (int r = 0; r < 4; ++r) {
        int f = wave * 32 + m * 16 + (lane >> 4) * 4 + r;
        pb[f * 65 + d] = acc[m][n][r];
      }
    }
  // reduce ks across the 4 lane>>4 groups (same lane&15, same wave)
  ks0 += __shfl_xor(ks0, 16); ks0 += __shfl_xor(ks0, 32);
  ks1 += __shfl_xor(ks1, 16); ks1 += __shfl_xor(ks1, 32);
  if ((lane >> 4) == 0) {
    pb[(wave * 32 + (lane & 15)) * 65 + 64] = ks0;
    pb[(wave * 32 + 16 + (lane & 15)) * 65 + 64] = ks1;
  }
}

// reduce partials -> KVT [bh][80 rows][128 f] bf16 (row 64 = Ksum, 65..79 = 0)
__global__ __launch_bounds__(256) void kv_reduce_kernel(
    const float* __restrict__ partial, u16* __restrict__ KVT) {
  const int bh = blockIdx.x >> 3, eo = (blockIdx.x & 7) * 1040;
  const int tid = threadIdx.x;
  for (int e = eo + tid; e < eo + 1040; e += 256) {
    float s = 0.f;
#pragma unroll
    for (int c = 0; c < 16; ++c) s += partial[(size_t)(bh * 16 + c) * 8320 + e];
    int f = e / 65, col = e % 65;
    KVT[((size_t)bh * 80 + col) * 128 + f] = f2bf(s);
  }
  if ((blockIdx.x & 7) == 7)
    for (int i = tid; i < 15 * 128; i += 256)
      KVT[((size_t)bh * 80 + 65) * 128 + i] = 0;
}

// ---------------- QKV = Qp @ KV, Z via 5th N-frag, divide -> A bf16 ----------------
__global__ __launch_bounds__(256) void qkv_div_kernel(
    const u16* __restrict__ Qp, const u16* __restrict__ KVT, u16* __restrict__ A) {
  __shared__ u16 smem2[26624];
  u16* Qs = smem2;          // [128 s][128 f]
  u16* Ks = smem2 + 16384;  // [80 rows][128 f]
  const int tid = threadIdx.x, lane = tid & 63, wave = tid >> 6;
  const int bh = blockIdx.x >> 6, st = blockIdx.x & 63;

  stage_r256<128>((const uint8_t*)(Qp + ((size_t)bh * 8192 + st * 128) * 128), 256,
                  Qs, wave, lane);
  stage_r256<80>((const uint8_t*)(KVT + (size_t)bh * 80 * 128), 256, Ks, wave, lane);
  __syncthreads();

  f32x4 acc[2][5];
#pragma unroll
  for (int m = 0; m < 2; ++m)
#pragma unroll
    for (int n = 0; n < 5; ++n) acc[m][n] = (f32x4){0.f, 0.f, 0.f, 0.f};

#pragma unroll
  for (int kk = 0; kk < 4; ++kk) {
    const int ko = kk * 32 + (lane >> 4) * 8;
    bf16x8 a[2], bb[5];
#pragma unroll
    for (int m = 0; m < 2; ++m)
      a[m] = *(const bf16x8*)&Qs[(size_t)(wave * 32 + m * 16 + (lane & 15)) * 128 + ko];
#pragma unroll
    for (int n = 0; n < 5; ++n)
      bb[n] = *(const bf16x8*)&Ks[(size_t)(n * 16 + (lane & 15)) * 128 + ko];
#pragma unroll
    for (int m = 0; m < 2; ++m)
#pragma unroll
      for (int n = 0; n < 5; ++n)
        acc[m][n] = __builtin_amdgcn_mfma_f32_16x16x32_bf16(a[m], bb[n], acc[m][n], 0, 0, 0);
  }

  const int b_ = bh >> 4, h = bh & 15;
#pragma unroll
  for (int m = 0; m < 2; ++m) {
#pragma unroll
    for (int r = 0; r < 4; ++r) {
      float z = fmaxf(__shfl(acc[m][4][r], lane & 48), 1e-6f);
      int srow = st * 128 + wave * 32 + m * 16 + (lane >> 4) * 4 + r;
      size_t rowb = ((size_t)b_ * 8192 + srow) * 1024 + h * 64;
#pragma unroll
      for (int n = 0; n < 4; ++n)
        A[rowb + n * 16 + (lane & 15)] = f2bf(acc[m][n][r] / z);
    }
  }
}

// ---------------- out = A @ Wo (fp32 out) ----------------
__global__ __launch_bounds__(256, 3) void gemm_out_kernel(
    const u16* __restrict__ A, const u16* __restrict__ WoT, float* __restrict__ out) {
  __shared__ u16 smem[16384];
  u16* As = smem;
  u16* Bs = smem + 8192;
  const int tid = threadIdx.x, lane = tid & 63, wave = tid >> 6;
  const int wr = wave >> 1, wc = wave & 1;
  const int nb = (blockIdx.x & 7) * 256 + (blockIdx.x >> 3);
  const int tn = nb & 7, tm = nb >> 3;

  f32x4 acc[4][4];
#pragma unroll
  for (int m = 0; m < 4; ++m)
#pragma unroll
    for (int n = 0; n < 4; ++n) acc[m][n] = (f32x4){0.f, 0.f, 0.f, 0.f};

  const uint8_t* aB = (const uint8_t*)(A + (size_t)tm * 128 * 1024);
  const uint8_t* bB = (const uint8_t*)(WoT + (size_t)tn * 128 * 1024);
  for (int kt = 0; kt < 16; ++kt) {
    stage128_sw(aB + kt * 128, 2048, As, wave, lane);
    stage128_sw(bB + kt * 128, 2048, Bs, wave, lane);
    __syncthreads();
    mma128_sw(As, Bs, acc, wr, wc, lane);
    __syncthreads();
  }

  const int rowbase = tm * 128 + wr * 64;
  const int colbase = tn * 128 + wc * 64;
#pragma unroll
  for (int m = 0; m < 4; ++m)
#pragma unroll
    for (int n = 0; n < 4; ++n) {
      int col = colbase + n * 16 + (lane & 15);
      int row = rowbase + m * 16 + (lane >> 4) * 4;
#pragma unroll
      for (int r = 0; r < 4; ++r)
        out[(size_t)(row + r) * 1024 + col] = acc[m][n][r];
    }
}

// ---------------- host ----------------

extern "C" void kernel_launch(void* const* d_in, const int* in_sizes, int n_in,
                              void* d_out, int out_size, void* d_ws, size_t ws_size,
                              hipStream_t stream) {
  const float* x  = (const float*)d_in[0];
  const float* Wq = (const float*)d_in[1];
  const float* Wk = (const float*)d_in[2];
  const float* Wv = (const float*)d_in[3];
  const float* Wo = (const float*)d_in[4];
  const float* rf = (const float*)d_in[5];
  float* out = (float*)d_out;

  if (ws_size < (size_t)411058176) return;   // fail cleanly, don't fault

  u16* ws = (u16*)d_ws;
  u16* xb    = ws;
  u16* Qp    = ws + 33554432UL;
  u16* KpT   = ws + 100663296UL;
  u16* VhT   = ws + 167772160UL;
  u16* wqkvT = ws + 201326592UL;
  u16* woT   = ws + 204472320UL;
  u16* rfT   = ws + 205520896UL;
  float* partial = (float*)xb;          // [1024][128][65] f32 (34 MB), alias xb
  u16* KVT   = wqkvT;                   // [64][80][128] bf16, alias wqkvT (dead)
  u16* Abuf  = xb;                      // [32768][1024] bf16, alias xb

  cast_x_kernel<<<4096, 256, 0, stream>>>(x, xb, 8388608L);
  transpose_cast4_kernel<<<4096, 256, 0, stream>>>(Wq, Wk, Wv, Wo, wqkvT, woT);
  transpose_cast_rf_kernel<<<8, 256, 0, stream>>>(rf, rfT);

  gemm_qkv_phi_kernel<<<6144, 256, 0, stream>>>(xb, wqkvT, rfT, Qp, KpT, VhT);
  kv_partial_kernel<<<1024, 256, 0, stream>>>(KpT, VhT, partial);
  kv_reduce_kernel<<<512, 256, 0, stream>>>(partial, KVT);
  qkv_div_kernel<<<4096, 256, 0, stream>>>(Qp, KVT, Abuf);
  gemm_out_kernel<<<2048, 256, 0, stream>>>(Abuf, woT, out);
}